// Round 19
// baseline (384.458 us; speedup 1.0000x reference)
//
#include <hip/hip_runtime.h>
#include <hip/hip_bf16.h>
#include <cstdint>
#include <cstddef>

typedef _Float16 f16;
typedef __attribute__((ext_vector_type(8))) _Float16 f16x8;   // MFMA A/B frag
typedef __attribute__((ext_vector_type(4))) float f32x4;      // MFMA C/D frag

#define DI __device__ __forceinline__

constexpr int BATCH  = 4096;
constexpr int S1     = 15;
constexpr int DPAD   = 128;   // 120 padded to 128
constexpr int H      = 512;
constexpr int OUTC   = 99;
constexpr int OUTPAD = 112;   // 99 padded to 7*16

// jax.nn.gelu (tanh approx) = x * sigmoid(2*0.79788456*(x+0.044715x^3)).
DI float gelu_tanh(float x) {
  float t = 1.5957691216057308f * (x + 0.044715f * x * x * x);
  return x / (1.f + __expf(-t));
}

// async 16B global -> LDS (wave-uniform LDS base + lane*16)
DI void gload16(const void* g, void* l) {
  __builtin_amdgcn_global_load_lds(
      (const __attribute__((address_space(1))) void*)g,
      (__attribute__((address_space(3))) void*)l, 16, 0, 0);
}

// counted waitcnt (vmcnt only) + barrier + sched pin
template<int N>
DI void wait_barrier() {
  if constexpr (N == 0)      asm volatile("s_waitcnt vmcnt(0)" ::: "memory");
  else if constexpr (N == 1) asm volatile("s_waitcnt vmcnt(1)" ::: "memory");
  else                       asm volatile("s_waitcnt vmcnt(3)" ::: "memory");
  __builtin_amdgcn_s_barrier();
  __builtin_amdgcn_sched_barrier(0);
}

// ---------------- embeddings: e[b][d] f16, d in [0,128), pad zeros -----------
__global__ void embed_kernel(const float* __restrict__ x, f16* __restrict__ e) {
  const int b = blockIdx.x, d = threadIdx.x;  // 128 threads
  float v = 0.f;
  if (d < 120) {
    const float divs[4] = {1.f, 0.31622776601683794f, 0.1f, 0.03162277660168379f};
    int site = d >> 3, j = d & 7;
    float arg = x[b * 16 + site] * divs[j & 3];
    v = (j < 4) ? sinf(arg) : cosf(arg);
  }
  e[b * DPAD + d] = (f16)v;
}

// ---- transpose+convert+split: dst{h,l}[s][n][k] = split_f16(src[s][k][n]) ---
__global__ __launch_bounds__(256) void transpose_conv_kernel(
    const float* __restrict__ src, f16* __restrict__ dsth, f16* __restrict__ dstl,
    int K, int N, int Kpad, int Npad, int maskMul) {
  __shared__ float tile[32][33];
  const int s  = blockIdx.z;
  const int kb = blockIdx.x * 32, nb = blockIdx.y * 32;
  const int tx = threadIdx.x & 31, ty = threadIdx.x >> 5;  // 32 x 8
  for (int i = ty; i < 32; i += 8) {
    int k = kb + i, n = nb + tx;
    tile[i][tx] = (k < K && n < N) ? src[((size_t)s * K + k) * N + n] : 0.f;
  }
  __syncthreads();
  const int klim = maskMul ? maskMul * (s + 1) : 0x7FFFFFFF;
  for (int i = ty; i < 32; i += 8) {
    int n = nb + i, k = kb + tx;
    if (n < Npad && k < Kpad) {
      float v = (k < klim) ? tile[tx][i] : 0.f;
      size_t o = ((size_t)s * Npad + n) * Kpad + k;
      f16 h = (f16)v;
      dsth[o] = h;
      dstl[o] = (f16)(v - (float)h);
    }
  }
}

// ---- GEMM, W-split f16 (2 MFMA), f32-y output (+bias +resid), no LN --------
// R19: BK 64->32 so LDS = A-ring2 (2x16K) + B-ring4 (4x8K) = 64KB -> TWO
// blocks/CU (4 waves/SIMD) -- R17/18's 128KB pinned 1 block/CU and the
// per-phase vmcnt waits had nothing to overlap with (T5 null confirmed
// lockstep). Same tile BM=256/BN=128 (staging-traffic optimal, 32MB/site),
// same depth-2 counted-vmcnt schedule, waits re-derived for loads/stage
// {A:2, B:1} (queue depth 4): even phase vmcnt(1), odd vmcnt(3), last 0.
// WAR: each buffer rewrite is issued after the barrier retiring its readers.
template<int NT, bool RES>
__global__ __launch_bounds__(512) void gemm_y_kernel(
    const f16* __restrict__ A, const f16* __restrict__ Wh, const f16* __restrict__ Wl,
    const float* __restrict__ bias, float* __restrict__ ybuf,
    int M, int Kd, int strideAS) {
  constexpr int BM = 256, BN = 128, BK = 32;
  constexpr int WM = 64, WN = 64, FM = 4, FN = 4;
  extern __shared__ f16 smem[];
  f16* const AR0 = smem;                    // 16KB
  f16* const AR1 = smem + BM * BK;          // 16KB
  f16* const BRb = smem + 2 * BM * BK;      // 4 x 8KB
  f16* const AR[2] = {AR0, AR1};
  f16* const BR[4] = {BRb, BRb + BN * BK, BRb + 2 * BN * BK, BRb + 3 * BN * BK};

  const int n    = gridDim.x;          // 64*nz, %8==0
  const int b    = blockIdx.x;
  const int w    = (b & 7) * (n >> 3) + (b >> 3);
  const int srel = w >> 6;             // 64 blocks per site
  const int rem  = w & 63;
  const int m0   = (rem >> 2) * BM;    // 16 m-blocks
  const int n0   = (rem & 3) * BN;     // 4 n-blocks

  const f16* ap  = A  + (size_t)srel * strideAS + (size_t)m0 * Kd;
  const f16* wph = Wh + ((size_t)srel * H + n0) * Kd;
  const f16* wpl = Wl + ((size_t)srel * H + n0) * Kd;
  const int tid = threadIdx.x, wbase = tid & ~63;
  const int wave = tid >> 6, lane = tid & 63;
  const int wr = wave >> 1, wc = wave & 1;   // 4m x 2n
  const int laneRow = lane & 15;
  const int hi      = lane >> 4;             // chunk index 0..3 (BK=32)

  // staging offsets (CPR=4): chunk idx = j*512 + tid; row = j*128 + (tid>>2);
  // c = tid&3; cg = c ^ (row&3) = (tid&3) ^ ((tid>>2)&3)   (j*128 % 4 == 0).
  const int rA  = tid >> 2;
  const int cg8 = (((tid & 3) ^ (rA & 3)) << 3);
  uint32_t offA[2];
#pragma unroll
  for (int j = 0; j < 2; ++j) offA[j] = (uint32_t)(j * 128 + rA) * (uint32_t)Kd + cg8;
  const uint32_t offB0 = (uint32_t)rA * (uint32_t)Kd + cg8;

  auto stageA = [&](uint32_t koff, f16* lds) {
#pragma unroll
    for (int j = 0; j < 2; ++j)
      gload16(ap + offA[j] + koff, lds + ((j * 512 + wbase) << 3));
  };
  auto stageB = [&](const f16* __restrict__ gbase, uint32_t koff, f16* lds) {
    gload16(gbase + offB0 + koff, lds + (wbase << 3));
  };

  f32x4 acc[FM][FN] = {};
  auto mma = [&](const f16* __restrict__ Ab, const f16* __restrict__ Bb) {
    __builtin_amdgcn_s_setprio(1);
    f16x8 a[FM];
#pragma unroll
    for (int mi = 0; mi < FM; ++mi) {
      const int row = wr * WM + mi * 16 + laneRow;
      a[mi] = *reinterpret_cast<const f16x8*>(&Ab[row * BK + ((hi ^ (row & 3)) << 3)]);
    }
#pragma unroll
    for (int ni = 0; ni < FN; ++ni) {
      const int row = wc * WN + ni * 16 + laneRow;
      f16x8 bv = *reinterpret_cast<const f16x8*>(&Bb[row * BK + ((hi ^ (row & 3)) << 3)]);
#pragma unroll
      for (int mi = 0; mi < FM; ++mi)
        acc[mi][ni] = __builtin_amdgcn_mfma_f32_16x16x32_f16(a[mi], bv, acc[mi][ni], 0, 0, 0);
    }
    __builtin_amdgcn_s_setprio(0);
  };

  // prologue: A(0):2, B(0)=Wh(0):1, B(1)=Wl(0):1  -> queue depth 4
  stageA(0, AR[0]);
  stageB(wph, 0, BR[0]);
  stageB(wpl, 0, BR[1]);

#pragma unroll
  for (int v = 0; v < 2 * NT; ++v) {
    if (v == 2 * NT - 1)      wait_barrier<0>();
    else if (v & 1)           wait_barrier<3>();
    else                      wait_barrier<1>();
    if ((v & 1) == 0 && (v / 2 + 1) < NT)
      stageA((uint32_t)(v / 2 + 1) * BK, AR[(v / 2 + 1) & 1]);
    if (v + 2 < 2 * NT) {
      const int u = v + 2;
      stageB((u & 1) ? wpl : wph, (uint32_t)(u >> 1) * BK, BR[u & 3]);
    }
    mma(AR[(v >> 1) & 1], BR[v & 3]);
  }
  __builtin_amdgcn_sched_barrier(0);

  // ---- epilogue: y = acc + bias (+resid), stored f32 (no rounding) ---------
#pragma unroll
  for (int ni = 0; ni < FN; ++ni) {
    const int colg = n0 + wc * WN + ni * 16 + laneRow;
    const float bvv = bias[srel * H + colg];
#pragma unroll
    for (int mi = 0; mi < FM; ++mi)
#pragma unroll
      for (int r = 0; r < 4; ++r) {
        const int row = wr * WM + mi * 16 + hi * 4 + r;
        float y = acc[mi][ni][r] + bvv;
        if constexpr (RES)
          y += (float)A[(size_t)srel * strideAS + (size_t)(m0 + row) * Kd + colg];
        ybuf[((size_t)srel * M + m0 + row) * H + colg] = y;
      }
  }
}

// ------- gelu + LayerNorm from f32 y -> f16 z; one wave per 512-row ---------
__global__ __launch_bounds__(256) void gelu_ln_f32_kernel(
    const float* __restrict__ ybuf, f16* __restrict__ zbuf,
    const float* __restrict__ lns, const float* __restrict__ lnb) {
  const int row  = blockIdx.x * 4 + (threadIdx.x >> 6);
  const int lane = threadIdx.x & 63;
  const float* yp = ybuf + (size_t)row * H + lane * 8;
  float4 v0 = *reinterpret_cast<const float4*>(yp);
  float4 v1 = *reinterpret_cast<const float4*>(yp + 4);
  float g[8];
  g[0] = gelu_tanh(v0.x); g[1] = gelu_tanh(v0.y); g[2] = gelu_tanh(v0.z); g[3] = gelu_tanh(v0.w);
  g[4] = gelu_tanh(v1.x); g[5] = gelu_tanh(v1.y); g[6] = gelu_tanh(v1.z); g[7] = gelu_tanh(v1.w);
  float sum = 0.f, sq = 0.f;
#pragma unroll
  for (int j = 0; j < 8; ++j) { sum += g[j]; sq += g[j] * g[j]; }
#pragma unroll
  for (int o = 32; o > 0; o >>= 1) {
    sum += __shfl_xor(sum, o, 64);
    sq  += __shfl_xor(sq, o, 64);
  }
  const float mean = sum * (1.f / 512.f);
  const float var  = sq * (1.f / 512.f) - mean * mean;
  const float rstd = 1.f / sqrtf(var + 1e-6f);
  const int site = row / BATCH;
  const float* sp = lns + site * H + lane * 8;
  const float* bp = lnb + site * H + lane * 8;
  f16x8 outv;
#pragma unroll
  for (int j = 0; j < 8; ++j)
    outv[j] = (f16)((g[j] - mean) * rstd * sp[j] + bp[j]);
  *reinterpret_cast<f16x8*>(&zbuf[(size_t)row * H + lane * 8]) = outv;
}

// ---- final projection GEMM, W-split f16 (2 MFMA), f32 out -------------------
__global__ __launch_bounds__(512) void gemm_out_kernel(
    const f16* __restrict__ A, const f16* __restrict__ Wh, const f16* __restrict__ Wl,
    const float* __restrict__ bias, float* __restrict__ out,
    int M, int Kd, int strideAS) {
  constexpr int BM = 128, BN = 112, BK = 64;
  constexpr int CPR = BK / 8, SWZ = CPR - 1;
  constexpr int FN = 7;
  extern __shared__ f16 smem[];
  f16* As  = smem;               // 128*64
  f16* Bhs = As + BM * BK;       // 112*64
  f16* Bls = Bhs + BN * BK;

  const int s  = blockIdx.z;
  const int m0 = blockIdx.x * BM;
  const f16* ap  = A  + (size_t)s * strideAS + (size_t)m0 * Kd;
  const f16* wph = Wh + (size_t)s * BN * Kd;
  const f16* wpl = Wl + (size_t)s * BN * Kd;
  const int tid = threadIdx.x, wbase = tid & ~63;
  const int wave = tid >> 6, lane = tid & 63;
  const int wr = wave;           // 16 rows per wave
  f32x4 acc[FN] = {};
  const int laneRow = lane & 15;
  const int hi      = lane >> 4;

  for (int k0 = 0; k0 < Kd; k0 += BK) {
    __syncthreads();
#pragma unroll
    for (int base = 0; base < BM * CPR; base += 512) {   // 1024 chunks
      const int idx = base + tid;
      const int r = idx / CPR, c = idx % CPR, cg = c ^ (r & SWZ);
      gload16(ap + (size_t)r * Kd + k0 + cg * 8, As + (size_t)(base + wbase) * 8);
    }
#pragma unroll
    for (int base = 0; base < BN * CPR; base += 512) {   // 896 chunks, partial
      const int idx = base + tid;
      if (idx < BN * CPR) {
        const int r = idx / CPR, c = idx % CPR, cg = c ^ (r & SWZ);
        const size_t go = (size_t)r * Kd + k0 + cg * 8;
        gload16(wph + go, Bhs + (size_t)(base + wbase) * 8);
        gload16(wpl + go, Bls + (size_t)(base + wbase) * 8);
      }
    }
    __syncthreads();
    __builtin_amdgcn_s_setprio(1);
#pragma unroll
    for (int kk = 0; kk < BK / 32; ++kk) {
      const int cc = kk * 4 + hi;
      const int rowA = wr * 16 + laneRow;
      f16x8 a = *reinterpret_cast<const f16x8*>(&As[rowA * BK + ((cc ^ (rowA & SWZ)) << 3)]);
#pragma unroll
      for (int ni = 0; ni < FN; ++ni) {
        const int row = ni * 16 + laneRow;
        const int off = row * BK + ((cc ^ (row & SWZ)) << 3);
        f16x8 bh = *reinterpret_cast<const f16x8*>(&Bhs[off]);
        f16x8 bl = *reinterpret_cast<const f16x8*>(&Bls[off]);
        acc[ni] = __builtin_amdgcn_mfma_f32_16x16x32_f16(a, bh, acc[ni], 0, 0, 0);
        acc[ni] = __builtin_amdgcn_mfma_f32_16x16x32_f16(a, bl, acc[ni], 0, 0, 0);
      }
    }
    __builtin_amdgcn_s_setprio(0);
  }

  const int rbase = hi * 4;
#pragma unroll
  for (int ni = 0; ni < FN; ++ni)
#pragma unroll
    for (int r = 0; r < 4; ++r) {
      const int gm = m0 + wr * 16 + rbase + r;
      const int gn = ni * 16 + laneRow;
      if (gn < OUTC)
        out[((size_t)s * M + gm) * OUTC + gn] = acc[ni][r] + bias[s * OUTC + gn];
    }
}

// ---------------- RQS spline: one thread per (b,i), params via LDS -----------
DI float invsymlu(float u) { return u >= 0.f ? u + 1.f : 1.f / (1.f - u); }

__global__ __launch_bounds__(128) void spline_kernel(
    const float* __restrict__ x, const float* __restrict__ bias0,
    const float* __restrict__ p, float* __restrict__ out0, float* __restrict__ ladbuf) {
  __shared__ float prm[128 * 101];   // stride 101: conflict-free
  const int i  = blockIdx.x;         // 0..15
  const int b0 = blockIdx.y * 128;
  if (i == 0) {
    for (int idx = threadIdx.x; idx < 128 * OUTC; idx += 128)
      prm[(idx / OUTC) * 101 + idx % OUTC] = bias0[idx % OUTC];
  } else {
    const float* src = p + ((size_t)(i - 1) * BATCH + b0) * OUTC;
    for (int idx = threadIdx.x; idx < 128 * OUTC; idx += 128)
      prm[(idx / OUTC) * 101 + idx % OUTC] = src[idx];
  }
  __syncthreads();
  const float* P = &prm[threadIdx.x * 101];
  const int b = b0 + threadIdx.x;
  const float inp = x[b * 16 + i];

  float tw = 0.f, th = 0.f;
  for (int k = 0; k < 32; ++k) tw += 0.001f + invsymlu(P[k]);
  for (int k = 0; k < 32; ++k) th += 0.001f + invsymlu(P[32 + k]);
  const float cx = P[97], cy = P[98];
  const float w0 = cx - 0.5f * tw, wK = cx + 0.5f * tw;
  const float h0 = cy - 0.5f * th, hK = cy + 0.5f * th;
  const float d0 = 0.001f + invsymlu(P[64]);
  const float dK = 0.001f + invsymlu(P[96]);
  float outv, lad;
  if (inp < w0) {
    outv = h0 - (w0 - inp) * d0;
    lad  = logf(d0);
  } else if (inp >= wK) {
    outv = (inp - wK) * dK + hK;
    lad  = logf(dK);
  } else {
    float run = w0, icw = w0, ibw = 1.f;
    int bin = 0;
    for (int k = 0; k < 32; ++k) {
      float wk = 0.001f + invsymlu(P[k]);
      if (inp >= run) { bin = k; icw = run; ibw = wk; }
      run += wk;
    }
    float runh = h0;
    for (int k = 0; k < bin; ++k) runh += 0.001f + invsymlu(P[32 + k]);
    const float ih    = 0.001f + invsymlu(P[32 + bin]);
    const float ich   = runh;
    const float ider  = 0.001f + invsymlu(P[64 + bin]);
    const float iderp = 0.001f + invsymlu(P[64 + bin + 1]);
    const float idl   = ih / ibw;
    const float theta = (inp - icw) / ibw;
    const float omt   = 1.f - theta;
    const float tomt  = theta * omt;
    const float num   = ih * (idl * theta * theta + ider * tomt);
    const float den   = idl + (ider + iderp - 2.f * idl) * tomt;
    outv = ich + num / den;
    const float dnum = idl * idl * (iderp * theta * theta + 2.f * idl * tomt + ider * omt * omt);
    lad = logf(dnum) - 2.f * logf(den);
  }
  out0[b * 16 + i]   = outv;
  ladbuf[b * 16 + i] = lad;
}

__global__ void lad_reduce_kernel(const float* __restrict__ ladbuf, float* __restrict__ out1) {
  const int b = blockIdx.x * 256 + threadIdx.x;
  float s = 0.f;
#pragma unroll
  for (int i = 0; i < 16; ++i) s += ladbuf[b * 16 + i];
  out1[b] = s;
}

// ---------------------------------------------------------------------------
extern "C" void kernel_launch(void* const* d_in, const int* in_sizes, int n_in,
                              void* d_out, int out_size, void* d_ws, size_t ws_size,
                              hipStream_t stream) {
  const float* x     = (const float*)d_in[0];
  const float* bias0 = (const float*)d_in[1];
  const float* W0    = (const float*)d_in[2];
  const float* b0    = (const float*)d_in[3];
  const float* ln0s  = (const float*)d_in[4];
  const float* ln0b  = (const float*)d_in[5];
  const float* W1    = (const float*)d_in[6];
  const float* b1    = (const float*)d_in[7];
  const float* ln1s  = (const float*)d_in[8];
  const float* ln1b  = (const float*)d_in[9];
  const float* W2    = (const float*)d_in[10];
  const float* b2    = (const float*)d_in[11];
  const float* ln2s  = (const float*)d_in[12];
  const float* ln2b  = (const float*)d_in[13];
  const float* Wf    = (const float*)d_in[14];
  const float* bfb   = (const float*)d_in[15];
  float* out0 = (float*)d_out;
  float* out1 = out0 + BATCH * 16;

  // ---- workspace budget ----------------------------------------------------
  const size_t fixedBytes =
      (size_t)BATCH * DPAD * 2 +                // e
      2 * ((size_t)S1 * H * DPAD * 2) +         // W0T h,l
      4 * ((size_t)S1 * H * H * 2) +            // W1T, W2T h,l
      2 * ((size_t)S1 * OUTPAD * H * 2) +       // WfT h,l
      (size_t)S1 * BATCH * OUTC * 4 +           // pbuf
      (size_t)BATCH * 16 * 4 +                  // ladb
      64 * 256;
  // per-site: y f32 (8MB) + P1 f16 (4MB) + P2 f16 (4MB)
  const size_t perSiteP = (size_t)BATCH * H * 4 + 2 * ((size_t)BATCH * H * 2);
  int CH = 1;
  if (ws_size > fixedBytes) {
    size_t c = (ws_size - fixedBytes) / perSiteP;
    CH = (c >= (size_t)S1) ? S1 : (c < 1 ? 1 : (int)c);
  }
  const int nPasses = (S1 + CH - 1) / CH;
  const int baseSz  = S1 / nPasses;
  const int remSz   = S1 % nPasses;

  char* ws = (char*)d_ws;
  size_t off = 0;
  auto take = [&](size_t bytes) {
    char* q = ws + off;
    off += (bytes + 255) & ~(size_t)255;
    return q;
  };
  f16* e     = (f16*)take((size_t)BATCH * DPAD * 2);
  f16* W0Th  = (f16*)take((size_t)S1 * H * DPAD * 2);
  f16* W0Tl  = (f16*)take((size_t)S1 * H * DPAD * 2);
  f16* W1Th  = (f16*)take((size_t)S1 * H * H * 2);
  f16* W1Tl  = (f16*)take((size_t)S1 * H * H * 2);
  f16* W2Th  = (f16*)take((size_t)S1 * H * H * 2);
  f16* W2Tl  = (f16*)take((size_t)S1 * H * H * 2);
  f16* WfTh  = (f16*)take((size_t)S1 * OUTPAD * H * 2);
  f16* WfTl  = (f16*)take((size_t)S1 * OUTPAD * H * 2);
  float* ybuf = (float*)take((size_t)CH * BATCH * H * 4);
  f16* P1    = (f16*)take((size_t)CH * BATCH * H * 2);
  f16* P2    = (f16*)take((size_t)CH * BATCH * H * 2);
  float* pbuf = (float*)take((size_t)S1 * BATCH * OUTC * 4);
  float* ladb = (float*)take((size_t)BATCH * 16 * 4);

  embed_kernel<<<BATCH, 128, 0, stream>>>(x, e);
  transpose_conv_kernel<<<dim3(4, 16, S1), 256, 0, stream>>>(W0, W0Th, W0Tl, 120, H, DPAD, H, 8);
  transpose_conv_kernel<<<dim3(16, 16, S1), 256, 0, stream>>>(W1, W1Th, W1Tl, H, H, H, H, 0);
  transpose_conv_kernel<<<dim3(16, 16, S1), 256, 0, stream>>>(W2, W2Th, W2Tl, H, H, H, H, 0);
  transpose_conv_kernel<<<dim3(16, 4, S1), 256, 0, stream>>>(Wf, WfTh, WfTl, H, OUTC, H, OUTPAD, 0);

  const size_t ldsGemm = (size_t)(2 * 256 + 4 * 128) * 32 * 2;  // 65536 B -> 2 blk/CU
  const size_t ldsOut  = (size_t)(128 + 112 + 112) * 64 * 2;    // 45056 B

  int sb = 0;
  for (int pass = 0; pass < nPasses; ++pass) {
    const int nz = baseSz + (pass < remSz ? 1 : 0);
    const int gridG = 64 * nz;        // %8==0
    const int gridL = nz * BATCH / 4;
    // layer 0: e (shared) -> y -> P2   (Kd=128 -> NT=4 at BK=32)
    gemm_y_kernel<4, false><<<gridG, 512, ldsGemm, stream>>>(
        e, W0Th + (size_t)sb * H * DPAD, W0Tl + (size_t)sb * H * DPAD,
        b0 + sb * H, ybuf, BATCH, DPAD, 0);
    gelu_ln_f32_kernel<<<gridL, 256, 0, stream>>>(ybuf, P2, ln0s + sb * H, ln0b + sb * H);
    // layer 1: P2 -> y (resid P2) -> P1   (Kd=512 -> NT=16)
    gemm_y_kernel<16, true><<<gridG, 512, ldsGemm, stream>>>(
        P2, W1Th + (size_t)sb * H * H, W1Tl + (size_t)sb * H * H,
        b1 + sb * H, ybuf, BATCH, H, BATCH * H);
    gelu_ln_f32_kernel<<<gridL, 256, 0, stream>>>(ybuf, P1, ln1s + sb * H, ln1b + sb * H);
    // layer 2: P1 -> y (resid P1) -> P2
    gemm_y_kernel<16, true><<<gridG, 512, ldsGemm, stream>>>(
        P1, W2Th + (size_t)sb * H * H, W2Tl + (size_t)sb * H * H,
        b2 + sb * H, ybuf, BATCH, H, BATCH * H);
    gelu_ln_f32_kernel<<<gridL, 256, 0, stream>>>(ybuf, P2, ln2s + sb * H, ln2b + sb * H);
    // final projection: P2 -> pbuf (f32)
    gemm_out_kernel<<<dim3(BATCH / 128, 1, nz), 512, ldsOut, stream>>>(
        P2, WfTh + (size_t)sb * OUTPAD * H, WfTl + (size_t)sb * OUTPAD * H,
        bfb + sb * OUTC, pbuf + (size_t)sb * BATCH * OUTC, BATCH, H, BATCH * H);
    sb += nz;
  }

  spline_kernel<<<dim3(16, 32), 128, 0, stream>>>(x, bias0, pbuf, out0, ladb);
  lad_reduce_kernel<<<BATCH / 256, 256, 0, stream>>>(ladb, out1);
}

// Round 21
// 357.566 us; speedup vs baseline: 1.0752x; 1.0752x over previous
//
#include <hip/hip_runtime.h>
#include <hip/hip_bf16.h>
#include <cstdint>
#include <cstddef>

typedef _Float16 f16;
typedef __attribute__((ext_vector_type(8))) _Float16 f16x8;   // MFMA A/B frag
typedef __attribute__((ext_vector_type(4))) float f32x4;      // MFMA C/D frag

#define DI __device__ __forceinline__

constexpr int BATCH  = 4096;
constexpr int S1     = 15;
constexpr int DPAD   = 128;   // 120 padded to 128
constexpr int H      = 512;
constexpr int OUTC   = 99;
constexpr int OUTPAD = 112;   // 99 padded to 7*16

// jax.nn.gelu (tanh approx) = x * sigmoid(2*0.79788456*(x+0.044715x^3)).
DI float gelu_tanh(float x) {
  float t = 1.5957691216057308f * (x + 0.044715f * x * x * x);
  return x / (1.f + __expf(-t));
}

// async 16B global -> LDS (wave-uniform LDS base + lane*16)
DI void gload16(const void* g, void* l) {
  __builtin_amdgcn_global_load_lds(
      (const __attribute__((address_space(1))) void*)g,
      (__attribute__((address_space(3))) void*)l, 16, 0, 0);
}

// ---------------- embeddings: e[b][d] f16, d in [0,128), pad zeros -----------
__global__ void embed_kernel(const float* __restrict__ x, f16* __restrict__ e) {
  const int b = blockIdx.x, d = threadIdx.x;  // 128 threads
  float v = 0.f;
  if (d < 120) {
    const float divs[4] = {1.f, 0.31622776601683794f, 0.1f, 0.03162277660168379f};
    int site = d >> 3, j = d & 7;
    float arg = x[b * 16 + site] * divs[j & 3];
    v = (j < 4) ? sinf(arg) : cosf(arg);
  }
  e[b * DPAD + d] = (f16)v;
}

// ---- transpose+convert+split: dst{h,l}[s][n][k] = split_f16(src[s][k][n]) ---
__global__ __launch_bounds__(256) void transpose_conv_kernel(
    const float* __restrict__ src, f16* __restrict__ dsth, f16* __restrict__ dstl,
    int K, int N, int Kpad, int Npad, int maskMul) {
  __shared__ float tile[32][33];
  const int s  = blockIdx.z;
  const int kb = blockIdx.x * 32, nb = blockIdx.y * 32;
  const int tx = threadIdx.x & 31, ty = threadIdx.x >> 5;  // 32 x 8
  for (int i = ty; i < 32; i += 8) {
    int k = kb + i, n = nb + tx;
    tile[i][tx] = (k < K && n < N) ? src[((size_t)s * K + k) * N + n] : 0.f;
  }
  __syncthreads();
  const int klim = maskMul ? maskMul * (s + 1) : 0x7FFFFFFF;
  for (int i = ty; i < 32; i += 8) {
    int n = nb + i, k = kb + tx;
    if (n < Npad && k < Kpad) {
      float v = (k < klim) ? tile[tx][i] : 0.f;
      size_t o = ((size_t)s * Npad + n) * Kpad + k;
      f16 h = (f16)v;
      dsth[o] = h;
      dstl[o] = (f16)(v - (float)h);
    }
  }
}

// ---- fused GEMM + gelu + LayerNorm, W-split f16 (2 MFMA), 2-phase pipeline --
// R21 = exact revert to R13 (proven best: 359us, absmax 0.28125).
// BM=64, BN=512, BK=64, 512 threads (8 waves 2mx4n), WM=32, WN=128.
// 16 virtual steps (8 K-tiles x {Wh,Wl}); B double-buffered (2x64KB) + A
// (2x8KB) = 144KB LDS. Each step: ISSUE next step's global_load_lds into the
// other buffer FIRST, then MFMA current buffer, then one barrier. The barrier's
// vmcnt(0) drain lands after the compute phase covered the load latency.
// NOTE (R20 lesson): counted-vmcnt needs depth-2 prefetch + wait-BEFORE-
// barrier (vmcnt is per-wave); depth-1 counted waits race. Full drain at the
// barrier is the correct depth-1 form.
// XCD-aware bijective swizzle: grid = 64*nz (%8==0); w=(b&7)*(n/8)+(b>>3).
template<bool RES>
__global__ __launch_bounds__(512) void gemm_ln_kernel(
    const f16* __restrict__ A, const f16* __restrict__ Wh, const f16* __restrict__ Wl,
    const float* __restrict__ bias, const float* __restrict__ lns,
    const float* __restrict__ lnb, f16* __restrict__ out,
    int M, int Kd, int strideAS) {
  constexpr int BM = 64, BN = 512, BK = 64;
  constexpr int CPR = BK / 8, SWZ = CPR - 1;
  constexpr int WM = 32, WN = 128, FM = 2, FN = 8;
  extern __shared__ f16 smem[];
  f16* const As0 = smem;                 // [2][BM*BK]  16KB
  f16* const Bs0 = smem + 2 * BM * BK;   // [2][BN*BK] 128KB

  const int n    = gridDim.x;
  const int b    = blockIdx.x;
  const int w    = (b & 7) * (n >> 3) + (b >> 3);
  const int srel = w >> 6;             // 64 m-blocks per site
  const int m0   = (w & 63) * BM;

  const f16* ap  = A  + (size_t)srel * strideAS + (size_t)m0 * Kd;
  const f16* wph = Wh + (size_t)srel * BN * Kd;
  const f16* wpl = Wl + (size_t)srel * BN * Kd;
  const int tid = threadIdx.x, wbase = tid & ~63;
  const int wave = tid >> 6, lane = tid & 63;
  const int wr = wave >> 2, wc = wave & 3;
  f32x4 acc[FM][FN] = {};
  const int laneRow = lane & 15;
  const int hi      = lane >> 4;

  // prologue: stage A(0) -> As0[0], Bh(0) -> Bs0[0]
  {
    const int r = tid / CPR, c = tid % CPR, cg = c ^ (r & SWZ);
    gload16(ap + (size_t)r * Kd + cg * 8, As0 + (size_t)wbase * 8);
  }
#pragma unroll
  for (int base = 0; base < BN * CPR; base += 512) {
    const int idx = base + tid;
    const int r = idx / CPR, c = idx % CPR, cg = c ^ (r & SWZ);
    gload16(wph + (size_t)r * Kd + cg * 8, Bs0 + (size_t)(base + wbase) * 8);
  }
  __syncthreads();

  const int NV = (Kd / BK) * 2;   // virtual steps: (ktile, {Wh,Wl})
  for (int v = 0; v < NV; ++v) {
    const int ktile = v >> 1;
    f16* const Acur = As0 + (size_t)(ktile & 1) * BM * BK;
    f16* const Bcur = Bs0 + (size_t)(v & 1) * BN * BK;
    // ---- issue next step's staging into the OTHER buffers ----
    if (v + 1 < NV) {
      const int nk = (v + 1) >> 1, np = (v + 1) & 1;
      if (np == 0) {   // new K-tile: stage its A
        f16* const Anxt = As0 + (size_t)(nk & 1) * BM * BK;
        const int r = tid / CPR, c = tid % CPR, cg = c ^ (r & SWZ);
        gload16(ap + (size_t)r * Kd + nk * BK + cg * 8, Anxt + (size_t)wbase * 8);
      }
      const f16* src = np ? wpl : wph;
      f16* const Bnxt = Bs0 + (size_t)((v + 1) & 1) * BN * BK;
#pragma unroll
      for (int base = 0; base < BN * CPR; base += 512) {
        const int idx = base + tid;
        const int r = idx / CPR, c = idx % CPR, cg = c ^ (r & SWZ);
        gload16(src + (size_t)r * Kd + nk * BK + cg * 8, Bnxt + (size_t)(base + wbase) * 8);
      }
    }
    // ---- compute current: acc += A(ktile) * B(v) ----
#pragma unroll
    for (int kk = 0; kk < BK / 32; ++kk) {
      const int cc = kk * 4 + hi;
      f16x8 a[FM];
#pragma unroll
      for (int mi = 0; mi < FM; ++mi) {
        const int row = wr * WM + mi * 16 + laneRow;
        a[mi] = *reinterpret_cast<const f16x8*>(&Acur[row * BK + ((cc ^ (row & SWZ)) << 3)]);
      }
#pragma unroll
      for (int ni = 0; ni < FN; ++ni) {
        const int row = wc * WN + ni * 16 + laneRow;
        f16x8 bv = *reinterpret_cast<const f16x8*>(&Bcur[row * BK + ((cc ^ (row & SWZ)) << 3)]);
#pragma unroll
        for (int mi = 0; mi < FM; ++mi)
          acc[mi][ni] = __builtin_amdgcn_mfma_f32_16x16x32_f16(a[mi], bv, acc[mi][ni], 0, 0, 0);
      }
    }
    __syncthreads();   // readers of current bufs done; next-step loads drained
  }

  // ---------------- fused epilogue: bias(+resid) -> gelu -> LN -> f16 -------
  const int rbase = hi * 4;
  float bv[FN], sv[FN], bb[FN];
#pragma unroll
  for (int ni = 0; ni < FN; ++ni) {
    const int gn = wc * WN + ni * 16 + laneRow;
    bv[ni] = bias[srel * H + gn];
    sv[ni] = lns[srel * H + gn];
    bb[ni] = lnb[srel * H + gn];
  }
  float lsum[FM][4], lsq[FM][4];
#pragma unroll
  for (int mi = 0; mi < FM; ++mi)
#pragma unroll
    for (int r = 0; r < 4; ++r) { lsum[mi][r] = 0.f; lsq[mi][r] = 0.f; }
#pragma unroll
  for (int mi = 0; mi < FM; ++mi)
#pragma unroll
    for (int r = 0; r < 4; ++r) {
      const int row = wr * WM + mi * 16 + rbase + r;
#pragma unroll
      for (int ni = 0; ni < FN; ++ni) {
        const int gn = wc * WN + ni * 16 + laneRow;
        float y = acc[mi][ni][r] + bv[ni];
        if constexpr (RES)
          y += (float)A[(size_t)srel * strideAS + (size_t)(m0 + row) * Kd + gn];
        float g = gelu_tanh(y);
        acc[mi][ni][r] = g;
        lsum[mi][r] += g;
        lsq[mi][r]  += g * g;
      }
    }
#pragma unroll
  for (int o = 1; o < 16; o <<= 1)
#pragma unroll
    for (int mi = 0; mi < FM; ++mi)
#pragma unroll
      for (int r = 0; r < 4; ++r) {
        lsum[mi][r] += __shfl_xor(lsum[mi][r], o, 64);
        lsq[mi][r]  += __shfl_xor(lsq[mi][r], o, 64);
      }
  __syncthreads();                       // all waves past K-loop LDS reads
  float* red = reinterpret_cast<float*>(smem);   // [64 rows][4 wc][2]
  if (laneRow == 0) {
#pragma unroll
    for (int mi = 0; mi < FM; ++mi)
#pragma unroll
      for (int r = 0; r < 4; ++r) {
        const int row = wr * WM + mi * 16 + rbase + r;
        red[(row * 4 + wc) * 2 + 0] = lsum[mi][r];
        red[(row * 4 + wc) * 2 + 1] = lsq[mi][r];
      }
  }
  __syncthreads();
#pragma unroll
  for (int mi = 0; mi < FM; ++mi)
#pragma unroll
    for (int r = 0; r < 4; ++r) {
      const int row = wr * WM + mi * 16 + rbase + r;
      float sum = 0.f, sq = 0.f;
#pragma unroll
      for (int w4 = 0; w4 < 4; ++w4) {
        sum += red[(row * 4 + w4) * 2 + 0];
        sq  += red[(row * 4 + w4) * 2 + 1];
      }
      const float mean = sum * (1.f / 512.f);
      const float var  = sq * (1.f / 512.f) - mean * mean;
      const float rstd = 1.f / sqrtf(var + 1e-6f);
#pragma unroll
      for (int ni = 0; ni < FN; ++ni) {
        const int gn = wc * WN + ni * 16 + laneRow;
        float z = (acc[mi][ni][r] - mean) * rstd * sv[ni] + bb[ni];
        out[((size_t)srel * M + m0 + row) * H + gn] = (f16)z;
      }
    }
}

// ---- final projection GEMM, W-split f16 (2 MFMA), f32 out -------------------
// BM=128, BN=112, BK=64, 512 threads (8 waves, WM=16, WN=112). No spill.
__global__ __launch_bounds__(512) void gemm_out_kernel(
    const f16* __restrict__ A, const f16* __restrict__ Wh, const f16* __restrict__ Wl,
    const float* __restrict__ bias, float* __restrict__ out,
    int M, int Kd, int strideAS) {
  constexpr int BM = 128, BN = 112, BK = 64;
  constexpr int CPR = BK / 8, SWZ = CPR - 1;
  constexpr int FN = 7;
  extern __shared__ f16 smem[];
  f16* As  = smem;               // 128*64
  f16* Bhs = As + BM * BK;       // 112*64
  f16* Bls = Bhs + BN * BK;

  const int s  = blockIdx.z;
  const int m0 = blockIdx.x * BM;
  const f16* ap  = A  + (size_t)s * strideAS + (size_t)m0 * Kd;
  const f16* wph = Wh + (size_t)s * BN * Kd;
  const f16* wpl = Wl + (size_t)s * BN * Kd;
  const int tid = threadIdx.x, wbase = tid & ~63;
  const int wave = tid >> 6, lane = tid & 63;
  const int wr = wave;           // 16 rows per wave
  f32x4 acc[FN] = {};
  const int laneRow = lane & 15;
  const int hi      = lane >> 4;

  for (int k0 = 0; k0 < Kd; k0 += BK) {
    __syncthreads();
#pragma unroll
    for (int base = 0; base < BM * CPR; base += 512) {   // 1024 chunks
      const int idx = base + tid;
      const int r = idx / CPR, c = idx % CPR, cg = c ^ (r & SWZ);
      gload16(ap + (size_t)r * Kd + k0 + cg * 8, As + (size_t)(base + wbase) * 8);
    }
#pragma unroll
    for (int base = 0; base < BN * CPR; base += 512) {   // 896 chunks, partial
      const int idx = base + tid;
      if (idx < BN * CPR) {
        const int r = idx / CPR, c = idx % CPR, cg = c ^ (r & SWZ);
        const size_t go = (size_t)r * Kd + k0 + cg * 8;
        gload16(wph + go, Bhs + (size_t)(base + wbase) * 8);
        gload16(wpl + go, Bls + (size_t)(base + wbase) * 8);
      }
    }
    __syncthreads();
#pragma unroll
    for (int kk = 0; kk < BK / 32; ++kk) {
      const int cc = kk * 4 + hi;
      const int rowA = wr * 16 + laneRow;
      f16x8 a = *reinterpret_cast<const f16x8*>(&As[rowA * BK + ((cc ^ (rowA & SWZ)) << 3)]);
#pragma unroll
      for (int ni = 0; ni < FN; ++ni) {
        const int row = ni * 16 + laneRow;
        const int off = row * BK + ((cc ^ (row & SWZ)) << 3);
        f16x8 bh = *reinterpret_cast<const f16x8*>(&Bhs[off]);
        f16x8 bl = *reinterpret_cast<const f16x8*>(&Bls[off]);
        acc[ni] = __builtin_amdgcn_mfma_f32_16x16x32_f16(a, bh, acc[ni], 0, 0, 0);
        acc[ni] = __builtin_amdgcn_mfma_f32_16x16x32_f16(a, bl, acc[ni], 0, 0, 0);
      }
    }
  }

  const int rbase = hi * 4;
#pragma unroll
  for (int ni = 0; ni < FN; ++ni)
#pragma unroll
    for (int r = 0; r < 4; ++r) {
      const int gm = m0 + wr * 16 + rbase + r;
      const int gn = ni * 16 + laneRow;
      if (gn < OUTC)
        out[((size_t)s * M + gm) * OUTC + gn] = acc[ni][r] + bias[s * OUTC + gn];
    }
}

// ---------------- RQS spline: one thread per (b,i), params via LDS -----------
DI float invsymlu(float u) { return u >= 0.f ? u + 1.f : 1.f / (1.f - u); }

__global__ __launch_bounds__(128) void spline_kernel(
    const float* __restrict__ x, const float* __restrict__ bias0,
    const float* __restrict__ p, float* __restrict__ out0, float* __restrict__ ladbuf) {
  __shared__ float prm[128 * 101];   // stride 101: conflict-free
  const int i  = blockIdx.x;         // 0..15
  const int b0 = blockIdx.y * 128;
  if (i == 0) {
    for (int idx = threadIdx.x; idx < 128 * OUTC; idx += 128)
      prm[(idx / OUTC) * 101 + idx % OUTC] = bias0[idx % OUTC];
  } else {
    const float* src = p + ((size_t)(i - 1) * BATCH + b0) * OUTC;
    for (int idx = threadIdx.x; idx < 128 * OUTC; idx += 128)
      prm[(idx / OUTC) * 101 + idx % OUTC] = src[idx];
  }
  __syncthreads();
  const float* P = &prm[threadIdx.x * 101];
  const int b = b0 + threadIdx.x;
  const float inp = x[b * 16 + i];

  float tw = 0.f, th = 0.f;
  for (int k = 0; k < 32; ++k) tw += 0.001f + invsymlu(P[k]);
  for (int k = 0; k < 32; ++k) th += 0.001f + invsymlu(P[32 + k]);
  const float cx = P[97], cy = P[98];
  const float w0 = cx - 0.5f * tw, wK = cx + 0.5f * tw;
  const float h0 = cy - 0.5f * th, hK = cy + 0.5f * th;
  const float d0 = 0.001f + invsymlu(P[64]);
  const float dK = 0.001f + invsymlu(P[96]);
  float outv, lad;
  if (inp < w0) {
    outv = h0 - (w0 - inp) * d0;
    lad  = logf(d0);
  } else if (inp >= wK) {
    outv = (inp - wK) * dK + hK;
    lad  = logf(dK);
  } else {
    float run = w0, icw = w0, ibw = 1.f;
    int bin = 0;
    for (int k = 0; k < 32; ++k) {
      float wk = 0.001f + invsymlu(P[k]);
      if (inp >= run) { bin = k; icw = run; ibw = wk; }
      run += wk;
    }
    float runh = h0;
    for (int k = 0; k < bin; ++k) runh += 0.001f + invsymlu(P[32 + k]);
    const float ih    = 0.001f + invsymlu(P[32 + bin]);
    const float ich   = runh;
    const float ider  = 0.001f + invsymlu(P[64 + bin]);
    const float iderp = 0.001f + invsymlu(P[64 + bin + 1]);
    const float idl   = ih / ibw;
    const float theta = (inp - icw) / ibw;
    const float omt   = 1.f - theta;
    const float tomt  = theta * omt;
    const float num   = ih * (idl * theta * theta + ider * tomt);
    const float den   = idl + (ider + iderp - 2.f * idl) * tomt;
    outv = ich + num / den;
    const float dnum = idl * idl * (iderp * theta * theta + 2.f * idl * tomt + ider * omt * omt);
    lad = logf(dnum) - 2.f * logf(den);
  }
  out0[b * 16 + i]   = outv;
  ladbuf[b * 16 + i] = lad;
}

__global__ void lad_reduce_kernel(const float* __restrict__ ladbuf, float* __restrict__ out1) {
  const int b = blockIdx.x * 256 + threadIdx.x;
  float s = 0.f;
#pragma unroll
  for (int i = 0; i < 16; ++i) s += ladbuf[b * 16 + i];
  out1[b] = s;
}

// ---------------------------------------------------------------------------
extern "C" void kernel_launch(void* const* d_in, const int* in_sizes, int n_in,
                              void* d_out, int out_size, void* d_ws, size_t ws_size,
                              hipStream_t stream) {
  const float* x     = (const float*)d_in[0];
  const float* bias0 = (const float*)d_in[1];
  const float* W0    = (const float*)d_in[2];
  const float* b0    = (const float*)d_in[3];
  const float* ln0s  = (const float*)d_in[4];
  const float* ln0b  = (const float*)d_in[5];
  const float* W1    = (const float*)d_in[6];
  const float* b1    = (const float*)d_in[7];
  const float* ln1s  = (const float*)d_in[8];
  const float* ln1b  = (const float*)d_in[9];
  const float* W2    = (const float*)d_in[10];
  const float* b2    = (const float*)d_in[11];
  const float* ln2s  = (const float*)d_in[12];
  const float* ln2b  = (const float*)d_in[13];
  const float* Wf    = (const float*)d_in[14];
  const float* bfb   = (const float*)d_in[15];
  float* out0 = (float*)d_out;
  float* out1 = out0 + BATCH * 16;

  // ---- workspace budget ----------------------------------------------------
  const size_t fixedBytes =
      (size_t)BATCH * DPAD * 2 +                // e
      2 * ((size_t)S1 * H * DPAD * 2) +         // W0T h,l
      4 * ((size_t)S1 * H * H * 2) +            // W1T, W2T h,l
      2 * ((size_t)S1 * OUTPAD * H * 2) +       // WfT h,l
      (size_t)S1 * BATCH * OUTC * 4 +           // pbuf
      (size_t)BATCH * 16 * 4 +                  // ladb
      64 * 256;
  const size_t perSiteP = 2 * ((size_t)BATCH * H * 2);  // P1+P2 per site
  int CH = 1;
  if (ws_size > fixedBytes) {
    size_t c = (ws_size - fixedBytes) / perSiteP;
    CH = (c >= (size_t)S1) ? S1 : (c < 1 ? 1 : (int)c);
  }
  const int nPasses = (S1 + CH - 1) / CH;
  const int baseSz  = S1 / nPasses;
  const int remSz   = S1 % nPasses;

  char* ws = (char*)d_ws;
  size_t off = 0;
  auto take = [&](size_t bytes) {
    char* q = ws + off;
    off += (bytes + 255) & ~(size_t)255;
    return q;
  };
  f16* e     = (f16*)take((size_t)BATCH * DPAD * 2);
  f16* W0Th  = (f16*)take((size_t)S1 * H * DPAD * 2);
  f16* W0Tl  = (f16*)take((size_t)S1 * H * DPAD * 2);
  f16* W1Th  = (f16*)take((size_t)S1 * H * H * 2);
  f16* W1Tl  = (f16*)take((size_t)S1 * H * H * 2);
  f16* W2Th  = (f16*)take((size_t)S1 * H * H * 2);
  f16* W2Tl  = (f16*)take((size_t)S1 * H * H * 2);
  f16* WfTh  = (f16*)take((size_t)S1 * OUTPAD * H * 2);
  f16* WfTl  = (f16*)take((size_t)S1 * OUTPAD * H * 2);
  f16* P1    = (f16*)take((size_t)CH * BATCH * H * 2);
  f16* P2    = (f16*)take((size_t)CH * BATCH * H * 2);
  float* pbuf = (float*)take((size_t)S1 * BATCH * OUTC * 4);
  float* ladb = (float*)take((size_t)BATCH * 16 * 4);

  embed_kernel<<<BATCH, 128, 0, stream>>>(x, e);
  transpose_conv_kernel<<<dim3(4, 16, S1), 256, 0, stream>>>(W0, W0Th, W0Tl, 120, H, DPAD, H, 8);
  transpose_conv_kernel<<<dim3(16, 16, S1), 256, 0, stream>>>(W1, W1Th, W1Tl, H, H, H, H, 0);
  transpose_conv_kernel<<<dim3(16, 16, S1), 256, 0, stream>>>(W2, W2Th, W2Tl, H, H, H, H, 0);
  transpose_conv_kernel<<<dim3(16, 4, S1), 256, 0, stream>>>(Wf, WfTh, WfTl, H, OUTC, H, OUTPAD, 0);

  const size_t ldsFused = (size_t)(2 * 64 + 2 * 512) * 64 * 2;   // 147456 B
  const size_t ldsOut   = (size_t)(128 + 112 + 112) * 64 * 2;    // 45056 B

  int sb = 0;
  for (int pass = 0; pass < nPasses; ++pass) {
    const int nz = baseSz + (pass < remSz ? 1 : 0);
    const int gridFused = (BATCH / 64) * nz;   // 64*nz, %8==0
    // layer 0: e (shared) -> P2  [fused gelu+LN]
    gemm_ln_kernel<false><<<gridFused, 512, ldsFused, stream>>>(
        e, W0Th + (size_t)sb * H * DPAD, W0Tl + (size_t)sb * H * DPAD,
        b0 + sb * H, ln0s + sb * H, ln0b + sb * H, P2, BATCH, DPAD, 0);
    // layer 1: P2 -> P1 (residual = P2)  [fused]
    gemm_ln_kernel<true><<<gridFused, 512, ldsFused, stream>>>(
        P2, W1Th + (size_t)sb * H * H, W1Tl + (size_t)sb * H * H,
        b1 + sb * H, ln1s + sb * H, ln1b + sb * H, P1, BATCH, H, BATCH * H);
    // layer 2: P1 -> P2 (residual = P1)  [fused]
    gemm_ln_kernel<true><<<gridFused, 512, ldsFused, stream>>>(
        P1, W2Th + (size_t)sb * H * H, W2Tl + (size_t)sb * H * H,
        b2 + sb * H, ln2s + sb * H, ln2b + sb * H, P2, BATCH, H, BATCH * H);
    // final projection: P2 -> pbuf (f32)
    gemm_out_kernel<<<dim3(BATCH / 128, 1, nz), 512, ldsOut, stream>>>(
        P2, WfTh + (size_t)sb * OUTPAD * H, WfTl + (size_t)sb * OUTPAD * H,
        bfb + sb * OUTC, pbuf + (size_t)sb * BATCH * OUTC, BATCH, H, BATCH * H);
    sb += nz;
  }

  spline_kernel<<<dim3(16, 32), 128, 0, stream>>>(x, bias0, pbuf, out0, ladb);
  lad_reduce_kernel<<<BATCH / 256, 256, 0, stream>>>(ladb, out1);
}

// Round 22
// 324.372 us; speedup vs baseline: 1.1852x; 1.1023x over previous
//
#include <hip/hip_runtime.h>
#include <hip/hip_bf16.h>
#include <cstdint>
#include <cstddef>

typedef _Float16 f16;
typedef __attribute__((ext_vector_type(8))) _Float16 f16x8;   // MFMA A/B frag
typedef __attribute__((ext_vector_type(4))) float f32x4;      // MFMA C/D frag

#define DI __device__ __forceinline__

constexpr int BATCH  = 4096;
constexpr int S1     = 15;
constexpr int DPAD   = 128;   // 120 padded to 128
constexpr int H      = 512;
constexpr int OUTC   = 99;
constexpr int OUTPAD = 112;   // 99 padded to 7*16

// jax.nn.gelu (tanh approx) = x * sigmoid(2*0.79788456*(x+0.044715x^3)).
DI float gelu_tanh(float x) {
  float t = 1.5957691216057308f * (x + 0.044715f * x * x * x);
  return x / (1.f + __expf(-t));
}

// async 16B global -> LDS (wave-uniform LDS base + lane*16)
DI void gload16(const void* g, void* l) {
  __builtin_amdgcn_global_load_lds(
      (const __attribute__((address_space(1))) void*)g,
      (__attribute__((address_space(3))) void*)l, 16, 0, 0);
}

// ---------------- embeddings: e[b][d] f16, d in [0,128), pad zeros -----------
__global__ void embed_kernel(const float* __restrict__ x, f16* __restrict__ e) {
  const int b = blockIdx.x, d = threadIdx.x;  // 128 threads
  float v = 0.f;
  if (d < 120) {
    const float divs[4] = {1.f, 0.31622776601683794f, 0.1f, 0.03162277660168379f};
    int site = d >> 3, j = d & 7;
    float arg = x[b * 16 + site] * divs[j & 3];
    v = (j < 4) ? sinf(arg) : cosf(arg);
  }
  e[b * DPAD + d] = (f16)v;
}

// ---- transpose+convert+split: dst{h,l}[s][n][k] = split_f16(src[s][k][n]) ---
__global__ __launch_bounds__(256) void transpose_conv_kernel(
    const float* __restrict__ src, f16* __restrict__ dsth, f16* __restrict__ dstl,
    int K, int N, int Kpad, int Npad, int maskMul) {
  __shared__ float tile[32][33];
  const int s  = blockIdx.z;
  const int kb = blockIdx.x * 32, nb = blockIdx.y * 32;
  const int tx = threadIdx.x & 31, ty = threadIdx.x >> 5;  // 32 x 8
  for (int i = ty; i < 32; i += 8) {
    int k = kb + i, n = nb + tx;
    tile[i][tx] = (k < K && n < N) ? src[((size_t)s * K + k) * N + n] : 0.f;
  }
  __syncthreads();
  const int klim = maskMul ? maskMul * (s + 1) : 0x7FFFFFFF;
  for (int i = ty; i < 32; i += 8) {
    int n = nb + i, k = kb + tx;
    if (n < Npad && k < Kpad) {
      float v = (k < klim) ? tile[tx][i] : 0.f;
      size_t o = ((size_t)s * Npad + n) * Kpad + k;
      f16 h = (f16)v;
      dsth[o] = h;
      if (dstl) dstl[o] = (f16)(v - (float)h);
    }
  }
}

// ---- fused GEMM + gelu + LayerNorm, optional W-split, 2-phase pipeline ------
// R22 = R13/R21 structure (proven best) + template<SPLIT>: SPLIT=true uses
// Wh+Wl (2 MFMA passes/tile, 16 phases); SPLIT=false uses Wh only (1 pass,
// 8 phases -> half the staged W bytes, the measured cost driver). Applied to
// layer 1 only (error model: +1 weight-rounding source -> absmax ~0.375).
// BM=64, BN=512, BK=64, 512 threads (8 waves 2mx4n), WM=32, WN=128.
// LDS 144KB = A-dbuf 2x8K + B-dbuf 2x64K. Each step: ISSUE next step's
// global_load_lds into the other buffer FIRST, then MFMA current, then one
// barrier (vmcnt(0) drain lands after compute covered load latency).
// Race check (both SPLIT values): every buffer rewrite is issued after the
// barrier that retired its readers (A[x]/B[x] last read >=1 phase earlier).
// XCD-aware bijective swizzle: grid = 64*nz (%8==0); w=(b&7)*(n/8)+(b>>3).
template<bool RES, bool SPLIT>
__global__ __launch_bounds__(512) void gemm_ln_kernel(
    const f16* __restrict__ A, const f16* __restrict__ Wh, const f16* __restrict__ Wl,
    const float* __restrict__ bias, const float* __restrict__ lns,
    const float* __restrict__ lnb, f16* __restrict__ out,
    int M, int Kd, int strideAS) {
  constexpr int BM = 64, BN = 512, BK = 64;
  constexpr int CPR = BK / 8, SWZ = CPR - 1;
  constexpr int WM = 32, WN = 128, FM = 2, FN = 8;
  extern __shared__ f16 smem[];
  f16* const As0 = smem;                 // [2][BM*BK]  16KB
  f16* const Bs0 = smem + 2 * BM * BK;   // [2][BN*BK] 128KB

  const int n    = gridDim.x;
  const int b    = blockIdx.x;
  const int w    = (b & 7) * (n >> 3) + (b >> 3);
  const int srel = w >> 6;             // 64 m-blocks per site
  const int m0   = (w & 63) * BM;

  const f16* ap  = A  + (size_t)srel * strideAS + (size_t)m0 * Kd;
  const f16* wph = Wh + (size_t)srel * BN * Kd;
  const f16* wpl = SPLIT ? (Wl + (size_t)srel * BN * Kd) : nullptr;
  const int tid = threadIdx.x, wbase = tid & ~63;
  const int wave = tid >> 6, lane = tid & 63;
  const int wr = wave >> 2, wc = wave & 3;
  f32x4 acc[FM][FN] = {};
  const int laneRow = lane & 15;
  const int hi      = lane >> 4;

  // prologue: stage A(0) -> As0[0], Wh(0) -> Bs0[0]
  {
    const int r = tid / CPR, c = tid % CPR, cg = c ^ (r & SWZ);
    gload16(ap + (size_t)r * Kd + cg * 8, As0 + (size_t)wbase * 8);
  }
#pragma unroll
  for (int base = 0; base < BN * CPR; base += 512) {
    const int idx = base + tid;
    const int r = idx / CPR, c = idx % CPR, cg = c ^ (r & SWZ);
    gload16(wph + (size_t)r * Kd + cg * 8, Bs0 + (size_t)(base + wbase) * 8);
  }
  __syncthreads();

  const int NT = Kd / BK;
  const int NV = SPLIT ? NT * 2 : NT;   // virtual steps
  for (int v = 0; v < NV; ++v) {
    const int ktile = SPLIT ? (v >> 1) : v;
    f16* const Acur = As0 + (size_t)(ktile & 1) * BM * BK;
    f16* const Bcur = Bs0 + (size_t)(v & 1) * BN * BK;
    // ---- issue next step's staging into the OTHER buffers ----
    if (v + 1 < NV) {
      const int nk = SPLIT ? ((v + 1) >> 1) : (v + 1);
      const bool newTile = SPLIT ? (((v + 1) & 1) == 0) : true;
      if (newTile) {   // new K-tile: stage its A
        f16* const Anxt = As0 + (size_t)(nk & 1) * BM * BK;
        const int r = tid / CPR, c = tid % CPR, cg = c ^ (r & SWZ);
        gload16(ap + (size_t)r * Kd + nk * BK + cg * 8, Anxt + (size_t)wbase * 8);
      }
      const f16* src = (SPLIT && ((v + 1) & 1)) ? wpl : wph;
      f16* const Bnxt = Bs0 + (size_t)((v + 1) & 1) * BN * BK;
#pragma unroll
      for (int base = 0; base < BN * CPR; base += 512) {
        const int idx = base + tid;
        const int r = idx / CPR, c = idx % CPR, cg = c ^ (r & SWZ);
        gload16(src + (size_t)r * Kd + nk * BK + cg * 8, Bnxt + (size_t)(base + wbase) * 8);
      }
    }
    // ---- compute current: acc += A(ktile) * B(v) ----
#pragma unroll
    for (int kk = 0; kk < BK / 32; ++kk) {
      const int cc = kk * 4 + hi;
      f16x8 a[FM];
#pragma unroll
      for (int mi = 0; mi < FM; ++mi) {
        const int row = wr * WM + mi * 16 + laneRow;
        a[mi] = *reinterpret_cast<const f16x8*>(&Acur[row * BK + ((cc ^ (row & SWZ)) << 3)]);
      }
#pragma unroll
      for (int ni = 0; ni < FN; ++ni) {
        const int row = wc * WN + ni * 16 + laneRow;
        f16x8 bv = *reinterpret_cast<const f16x8*>(&Bcur[row * BK + ((cc ^ (row & SWZ)) << 3)]);
#pragma unroll
        for (int mi = 0; mi < FM; ++mi)
          acc[mi][ni] = __builtin_amdgcn_mfma_f32_16x16x32_f16(a[mi], bv, acc[mi][ni], 0, 0, 0);
      }
    }
    __syncthreads();   // readers of current bufs done; next-step loads drained
  }

  // ---------------- fused epilogue: bias(+resid) -> gelu -> LN -> f16 -------
  const int rbase = hi * 4;
  float bv[FN], sv[FN], bb[FN];
#pragma unroll
  for (int ni = 0; ni < FN; ++ni) {
    const int gn = wc * WN + ni * 16 + laneRow;
    bv[ni] = bias[srel * H + gn];
    sv[ni] = lns[srel * H + gn];
    bb[ni] = lnb[srel * H + gn];
  }
  float lsum[FM][4], lsq[FM][4];
#pragma unroll
  for (int mi = 0; mi < FM; ++mi)
#pragma unroll
    for (int r = 0; r < 4; ++r) { lsum[mi][r] = 0.f; lsq[mi][r] = 0.f; }
#pragma unroll
  for (int mi = 0; mi < FM; ++mi)
#pragma unroll
    for (int r = 0; r < 4; ++r) {
      const int row = wr * WM + mi * 16 + rbase + r;
#pragma unroll
      for (int ni = 0; ni < FN; ++ni) {
        const int gn = wc * WN + ni * 16 + laneRow;
        float y = acc[mi][ni][r] + bv[ni];
        if constexpr (RES)
          y += (float)A[(size_t)srel * strideAS + (size_t)(m0 + row) * Kd + gn];
        float g = gelu_tanh(y);
        acc[mi][ni][r] = g;
        lsum[mi][r] += g;
        lsq[mi][r]  += g * g;
      }
    }
#pragma unroll
  for (int o = 1; o < 16; o <<= 1)
#pragma unroll
    for (int mi = 0; mi < FM; ++mi)
#pragma unroll
      for (int r = 0; r < 4; ++r) {
        lsum[mi][r] += __shfl_xor(lsum[mi][r], o, 64);
        lsq[mi][r]  += __shfl_xor(lsq[mi][r], o, 64);
      }
  __syncthreads();                       // all waves past K-loop LDS reads
  float* red = reinterpret_cast<float*>(smem);   // [64 rows][4 wc][2]
  if (laneRow == 0) {
#pragma unroll
    for (int mi = 0; mi < FM; ++mi)
#pragma unroll
      for (int r = 0; r < 4; ++r) {
        const int row = wr * WM + mi * 16 + rbase + r;
        red[(row * 4 + wc) * 2 + 0] = lsum[mi][r];
        red[(row * 4 + wc) * 2 + 1] = lsq[mi][r];
      }
  }
  __syncthreads();
#pragma unroll
  for (int mi = 0; mi < FM; ++mi)
#pragma unroll
    for (int r = 0; r < 4; ++r) {
      const int row = wr * WM + mi * 16 + rbase + r;
      float sum = 0.f, sq = 0.f;
#pragma unroll
      for (int w4 = 0; w4 < 4; ++w4) {
        sum += red[(row * 4 + w4) * 2 + 0];
        sq  += red[(row * 4 + w4) * 2 + 1];
      }
      const float mean = sum * (1.f / 512.f);
      const float var  = sq * (1.f / 512.f) - mean * mean;
      const float rstd = 1.f / sqrtf(var + 1e-6f);
#pragma unroll
      for (int ni = 0; ni < FN; ++ni) {
        const int gn = wc * WN + ni * 16 + laneRow;
        float z = (acc[mi][ni][r] - mean) * rstd * sv[ni] + bb[ni];
        out[((size_t)srel * M + m0 + row) * H + gn] = (f16)z;
      }
    }
}

// ---- final projection GEMM, W-split f16 (2 MFMA), f32 out -------------------
__global__ __launch_bounds__(512) void gemm_out_kernel(
    const f16* __restrict__ A, const f16* __restrict__ Wh, const f16* __restrict__ Wl,
    const float* __restrict__ bias, float* __restrict__ out,
    int M, int Kd, int strideAS) {
  constexpr int BM = 128, BN = 112, BK = 64;
  constexpr int CPR = BK / 8, SWZ = CPR - 1;
  constexpr int FN = 7;
  extern __shared__ f16 smem[];
  f16* As  = smem;               // 128*64
  f16* Bhs = As + BM * BK;       // 112*64
  f16* Bls = Bhs + BN * BK;

  const int s  = blockIdx.z;
  const int m0 = blockIdx.x * BM;
  const f16* ap  = A  + (size_t)s * strideAS + (size_t)m0 * Kd;
  const f16* wph = Wh + (size_t)s * BN * Kd;
  const f16* wpl = Wl + (size_t)s * BN * Kd;
  const int tid = threadIdx.x, wbase = tid & ~63;
  const int wave = tid >> 6, lane = tid & 63;
  const int wr = wave;           // 16 rows per wave
  f32x4 acc[FN] = {};
  const int laneRow = lane & 15;
  const int hi      = lane >> 4;

  for (int k0 = 0; k0 < Kd; k0 += BK) {
    __syncthreads();
#pragma unroll
    for (int base = 0; base < BM * CPR; base += 512) {   // 1024 chunks
      const int idx = base + tid;
      const int r = idx / CPR, c = idx % CPR, cg = c ^ (r & SWZ);
      gload16(ap + (size_t)r * Kd + k0 + cg * 8, As + (size_t)(base + wbase) * 8);
    }
#pragma unroll
    for (int base = 0; base < BN * CPR; base += 512) {   // 896 chunks, partial
      const int idx = base + tid;
      if (idx < BN * CPR) {
        const int r = idx / CPR, c = idx % CPR, cg = c ^ (r & SWZ);
        const size_t go = (size_t)r * Kd + k0 + cg * 8;
        gload16(wph + go, Bhs + (size_t)(base + wbase) * 8);
        gload16(wpl + go, Bls + (size_t)(base + wbase) * 8);
      }
    }
    __syncthreads();
#pragma unroll
    for (int kk = 0; kk < BK / 32; ++kk) {
      const int cc = kk * 4 + hi;
      const int rowA = wr * 16 + laneRow;
      f16x8 a = *reinterpret_cast<const f16x8*>(&As[rowA * BK + ((cc ^ (rowA & SWZ)) << 3)]);
#pragma unroll
      for (int ni = 0; ni < FN; ++ni) {
        const int row = ni * 16 + laneRow;
        const int off = row * BK + ((cc ^ (row & SWZ)) << 3);
        f16x8 bh = *reinterpret_cast<const f16x8*>(&Bhs[off]);
        f16x8 bl = *reinterpret_cast<const f16x8*>(&Bls[off]);
        acc[ni] = __builtin_amdgcn_mfma_f32_16x16x32_f16(a, bh, acc[ni], 0, 0, 0);
        acc[ni] = __builtin_amdgcn_mfma_f32_16x16x32_f16(a, bl, acc[ni], 0, 0, 0);
      }
    }
  }

  const int rbase = hi * 4;
#pragma unroll
  for (int ni = 0; ni < FN; ++ni)
#pragma unroll
    for (int r = 0; r < 4; ++r) {
      const int gm = m0 + wr * 16 + rbase + r;
      const int gn = ni * 16 + laneRow;
      if (gn < OUTC)
        out[((size_t)s * M + gm) * OUTC + gn] = acc[ni][r] + bias[s * OUTC + gn];
    }
}

// ---------------- RQS spline: one thread per (b,i), params via LDS -----------
DI float invsymlu(float u) { return u >= 0.f ? u + 1.f : 1.f / (1.f - u); }

__global__ __launch_bounds__(128) void spline_kernel(
    const float* __restrict__ x, const float* __restrict__ bias0,
    const float* __restrict__ p, float* __restrict__ out0, float* __restrict__ ladbuf) {
  __shared__ float prm[128 * 101];   // stride 101: conflict-free
  const int i  = blockIdx.x;         // 0..15
  const int b0 = blockIdx.y * 128;
  if (i == 0) {
    for (int idx = threadIdx.x; idx < 128 * OUTC; idx += 128)
      prm[(idx / OUTC) * 101 + idx % OUTC] = bias0[idx % OUTC];
  } else {
    const float* src = p + ((size_t)(i - 1) * BATCH + b0) * OUTC;
    for (int idx = threadIdx.x; idx < 128 * OUTC; idx += 128)
      prm[(idx / OUTC) * 101 + idx % OUTC] = src[idx];
  }
  __syncthreads();
  const float* P = &prm[threadIdx.x * 101];
  const int b = b0 + threadIdx.x;
  const float inp = x[b * 16 + i];

  float tw = 0.f, th = 0.f;
  for (int k = 0; k < 32; ++k) tw += 0.001f + invsymlu(P[k]);
  for (int k = 0; k < 32; ++k) th += 0.001f + invsymlu(P[32 + k]);
  const float cx = P[97], cy = P[98];
  const float w0 = cx - 0.5f * tw, wK = cx + 0.5f * tw;
  const float h0 = cy - 0.5f * th, hK = cy + 0.5f * th;
  const float d0 = 0.001f + invsymlu(P[64]);
  const float dK = 0.001f + invsymlu(P[96]);
  float outv, lad;
  if (inp < w0) {
    outv = h0 - (w0 - inp) * d0;
    lad  = logf(d0);
  } else if (inp >= wK) {
    outv = (inp - wK) * dK + hK;
    lad  = logf(dK);
  } else {
    float run = w0, icw = w0, ibw = 1.f;
    int bin = 0;
    for (int k = 0; k < 32; ++k) {
      float wk = 0.001f + invsymlu(P[k]);
      if (inp >= run) { bin = k; icw = run; ibw = wk; }
      run += wk;
    }
    float runh = h0;
    for (int k = 0; k < bin; ++k) runh += 0.001f + invsymlu(P[32 + k]);
    const float ih    = 0.001f + invsymlu(P[32 + bin]);
    const float ich   = runh;
    const float ider  = 0.001f + invsymlu(P[64 + bin]);
    const float iderp = 0.001f + invsymlu(P[64 + bin + 1]);
    const float idl   = ih / ibw;
    const float theta = (inp - icw) / ibw;
    const float omt   = 1.f - theta;
    const float tomt  = theta * omt;
    const float num   = ih * (idl * theta * theta + ider * tomt);
    const float den   = idl + (ider + iderp - 2.f * idl) * tomt;
    outv = ich + num / den;
    const float dnum = idl * idl * (iderp * theta * theta + 2.f * idl * tomt + ider * omt * omt);
    lad = logf(dnum) - 2.f * logf(den);
  }
  out0[b * 16 + i]   = outv;
  ladbuf[b * 16 + i] = lad;
}

__global__ void lad_reduce_kernel(const float* __restrict__ ladbuf, float* __restrict__ out1) {
  const int b = blockIdx.x * 256 + threadIdx.x;
  float s = 0.f;
#pragma unroll
  for (int i = 0; i < 16; ++i) s += ladbuf[b * 16 + i];
  out1[b] = s;
}

// ---------------------------------------------------------------------------
extern "C" void kernel_launch(void* const* d_in, const int* in_sizes, int n_in,
                              void* d_out, int out_size, void* d_ws, size_t ws_size,
                              hipStream_t stream) {
  const float* x     = (const float*)d_in[0];
  const float* bias0 = (const float*)d_in[1];
  const float* W0    = (const float*)d_in[2];
  const float* b0    = (const float*)d_in[3];
  const float* ln0s  = (const float*)d_in[4];
  const float* ln0b  = (const float*)d_in[5];
  const float* W1    = (const float*)d_in[6];
  const float* b1    = (const float*)d_in[7];
  const float* ln1s  = (const float*)d_in[8];
  const float* ln1b  = (const float*)d_in[9];
  const float* W2    = (const float*)d_in[10];
  const float* b2    = (const float*)d_in[11];
  const float* ln2s  = (const float*)d_in[12];
  const float* ln2b  = (const float*)d_in[13];
  const float* Wf    = (const float*)d_in[14];
  const float* bfb   = (const float*)d_in[15];
  float* out0 = (float*)d_out;
  float* out1 = out0 + BATCH * 16;

  // ---- workspace budget ----------------------------------------------------
  const size_t fixedBytes =
      (size_t)BATCH * DPAD * 2 +                // e
      2 * ((size_t)S1 * H * DPAD * 2) +         // W0T h,l
      3 * ((size_t)S1 * H * H * 2) +            // W1T h + W2T h,l
      2 * ((size_t)S1 * OUTPAD * H * 2) +       // WfT h,l
      (size_t)S1 * BATCH * OUTC * 4 +           // pbuf
      (size_t)BATCH * 16 * 4 +                  // ladb
      64 * 256;
  const size_t perSiteP = 2 * ((size_t)BATCH * H * 2);  // P1+P2 per site
  int CH = 1;
  if (ws_size > fixedBytes) {
    size_t c = (ws_size - fixedBytes) / perSiteP;
    CH = (c >= (size_t)S1) ? S1 : (c < 1 ? 1 : (int)c);
  }
  const int nPasses = (S1 + CH - 1) / CH;
  const int baseSz  = S1 / nPasses;
  const int remSz   = S1 % nPasses;

  char* ws = (char*)d_ws;
  size_t off = 0;
  auto take = [&](size_t bytes) {
    char* q = ws + off;
    off += (bytes + 255) & ~(size_t)255;
    return q;
  };
  f16* e     = (f16*)take((size_t)BATCH * DPAD * 2);
  f16* W0Th  = (f16*)take((size_t)S1 * H * DPAD * 2);
  f16* W0Tl  = (f16*)take((size_t)S1 * H * DPAD * 2);
  f16* W1Th  = (f16*)take((size_t)S1 * H * H * 2);   // single-f16 (no split)
  f16* W2Th  = (f16*)take((size_t)S1 * H * H * 2);
  f16* W2Tl  = (f16*)take((size_t)S1 * H * H * 2);
  f16* WfTh  = (f16*)take((size_t)S1 * OUTPAD * H * 2);
  f16* WfTl  = (f16*)take((size_t)S1 * OUTPAD * H * 2);
  f16* P1    = (f16*)take((size_t)CH * BATCH * H * 2);
  f16* P2    = (f16*)take((size_t)CH * BATCH * H * 2);
  float* pbuf = (float*)take((size_t)S1 * BATCH * OUTC * 4);
  float* ladb = (float*)take((size_t)BATCH * 16 * 4);

  embed_kernel<<<BATCH, 128, 0, stream>>>(x, e);
  transpose_conv_kernel<<<dim3(4, 16, S1), 256, 0, stream>>>(W0, W0Th, W0Tl, 120, H, DPAD, H, 8);
  transpose_conv_kernel<<<dim3(16, 16, S1), 256, 0, stream>>>(W1, W1Th, nullptr, H, H, H, H, 0);
  transpose_conv_kernel<<<dim3(16, 16, S1), 256, 0, stream>>>(W2, W2Th, W2Tl, H, H, H, H, 0);
  transpose_conv_kernel<<<dim3(16, 4, S1), 256, 0, stream>>>(Wf, WfTh, WfTl, H, OUTC, H, OUTPAD, 0);

  const size_t ldsFused = (size_t)(2 * 64 + 2 * 512) * 64 * 2;   // 147456 B
  const size_t ldsOut   = (size_t)(128 + 112 + 112) * 64 * 2;    // 45056 B

  int sb = 0;
  for (int pass = 0; pass < nPasses; ++pass) {
    const int nz = baseSz + (pass < remSz ? 1 : 0);
    const int gridFused = (BATCH / 64) * nz;   // 64*nz, %8==0
    // layer 0: e (shared) -> P2  [fused gelu+LN, W-split]
    gemm_ln_kernel<false, true><<<gridFused, 512, ldsFused, stream>>>(
        e, W0Th + (size_t)sb * H * DPAD, W0Tl + (size_t)sb * H * DPAD,
        b0 + sb * H, ln0s + sb * H, ln0b + sb * H, P2, BATCH, DPAD, 0);
    // layer 1: P2 -> P1 (residual = P2)  [fused, SINGLE-f16 W1 -> 8 phases]
    gemm_ln_kernel<true, false><<<gridFused, 512, ldsFused, stream>>>(
        P2, W1Th + (size_t)sb * H * H, nullptr,
        b1 + sb * H, ln1s + sb * H, ln1b + sb * H, P1, BATCH, H, BATCH * H);
    // layer 2: P1 -> P2 (residual = P1)  [fused, W-split]
    gemm_ln_kernel<true, true><<<gridFused, 512, ldsFused, stream>>>(
        P1, W2Th + (size_t)sb * H * H, W2Tl + (size_t)sb * H * H,
        b2 + sb * H, ln2s + sb * H, ln2b + sb * H, P2, BATCH, H, BATCH * H);
    // final projection: P2 -> pbuf (f32)
    gemm_out_kernel<<<dim3(BATCH / 128, 1, nz), 512, ldsOut, stream>>>(
        P2, WfTh + (size_t)sb * OUTPAD * H, WfTl + (size_t)sb * OUTPAD * H,
        bfb + sb * OUTC, pbuf + (size_t)sb * BATCH * OUTC, BATCH, H, BATCH * H);
    sb += nz;
  }

  spline_kernel<<<dim3(16, 32), 128, 0, stream>>>(x, bias0, pbuf, out0, ladb);
  lad_reduce_kernel<<<BATCH / 256, 256, 0, stream>>>(ladb, out1);
}

// Round 23
// 293.578 us; speedup vs baseline: 1.3096x; 1.1049x over previous
//
#include <hip/hip_runtime.h>
#include <hip/hip_bf16.h>
#include <cstdint>
#include <cstddef>

typedef _Float16 f16;
typedef __attribute__((ext_vector_type(8))) _Float16 f16x8;   // MFMA A/B frag
typedef __attribute__((ext_vector_type(4))) float f32x4;      // MFMA C/D frag

#define DI __device__ __forceinline__

constexpr int BATCH  = 4096;
constexpr int S1     = 15;
constexpr int DPAD   = 128;   // 120 padded to 128
constexpr int H      = 512;
constexpr int OUTC   = 99;
constexpr int OUTPAD = 112;   // 99 padded to 7*16

// jax.nn.gelu (tanh approx) = x * sigmoid(2*0.79788456*(x+0.044715x^3)).
DI float gelu_tanh(float x) {
  float t = 1.5957691216057308f * (x + 0.044715f * x * x * x);
  return x / (1.f + __expf(-t));
}

// async 16B global -> LDS (wave-uniform LDS base + lane*16)
DI void gload16(const void* g, void* l) {
  __builtin_amdgcn_global_load_lds(
      (const __attribute__((address_space(1))) void*)g,
      (__attribute__((address_space(3))) void*)l, 16, 0, 0);
}

// ---------------- embeddings: e[b][d] f16, d in [0,128), pad zeros -----------
__global__ void embed_kernel(const float* __restrict__ x, f16* __restrict__ e) {
  const int b = blockIdx.x, d = threadIdx.x;  // 128 threads
  float v = 0.f;
  if (d < 120) {
    const float divs[4] = {1.f, 0.31622776601683794f, 0.1f, 0.03162277660168379f};
    int site = d >> 3, j = d & 7;
    float arg = x[b * 16 + site] * divs[j & 3];
    v = (j < 4) ? sinf(arg) : cosf(arg);
  }
  e[b * DPAD + d] = (f16)v;
}

// ---- transpose+convert+split: dst{h,l}[s][n][k] = split_f16(src[s][k][n]) ---
__global__ __launch_bounds__(256) void transpose_conv_kernel(
    const float* __restrict__ src, f16* __restrict__ dsth, f16* __restrict__ dstl,
    int K, int N, int Kpad, int Npad, int maskMul) {
  __shared__ float tile[32][33];
  const int s  = blockIdx.z;
  const int kb = blockIdx.x * 32, nb = blockIdx.y * 32;
  const int tx = threadIdx.x & 31, ty = threadIdx.x >> 5;  // 32 x 8
  for (int i = ty; i < 32; i += 8) {
    int k = kb + i, n = nb + tx;
    tile[i][tx] = (k < K && n < N) ? src[((size_t)s * K + k) * N + n] : 0.f;
  }
  __syncthreads();
  const int klim = maskMul ? maskMul * (s + 1) : 0x7FFFFFFF;
  for (int i = ty; i < 32; i += 8) {
    int n = nb + i, k = kb + tx;
    if (n < Npad && k < Kpad) {
      float v = (k < klim) ? tile[tx][i] : 0.f;
      size_t o = ((size_t)s * Npad + n) * Kpad + k;
      f16 h = (f16)v;
      dsth[o] = h;
      if (dstl) dstl[o] = (f16)(v - (float)h);
    }
  }
}

// ---- fused GEMM + gelu + LayerNorm, optional W-split, 2-phase pipeline ------
// R23 = R22 + W2 also single-f16 (R22 measured: dropping W1's split moved
// absmax 0.28125 -> 0.25, i.e. weight-split contribution ~0; same lever on
// W2 saves another ~63us). W0 and Wf keep the split as precision anchors.
// BM=64, BN=512, BK=64, 512 threads (8 waves 2mx4n), WM=32, WN=128.
// LDS 144KB = A-dbuf 2x8K + B-dbuf 2x64K. Each step: ISSUE next step's
// global_load_lds into the other buffer FIRST, then MFMA current, then one
// barrier (vmcnt(0) drain lands after compute covered load latency).
// XCD-aware bijective swizzle: grid = 64*nz (%8==0); w=(b&7)*(n/8)+(b>>3).
template<bool RES, bool SPLIT>
__global__ __launch_bounds__(512) void gemm_ln_kernel(
    const f16* __restrict__ A, const f16* __restrict__ Wh, const f16* __restrict__ Wl,
    const float* __restrict__ bias, const float* __restrict__ lns,
    const float* __restrict__ lnb, f16* __restrict__ out,
    int M, int Kd, int strideAS) {
  constexpr int BM = 64, BN = 512, BK = 64;
  constexpr int CPR = BK / 8, SWZ = CPR - 1;
  constexpr int WM = 32, WN = 128, FM = 2, FN = 8;
  extern __shared__ f16 smem[];
  f16* const As0 = smem;                 // [2][BM*BK]  16KB
  f16* const Bs0 = smem + 2 * BM * BK;   // [2][BN*BK] 128KB

  const int n    = gridDim.x;
  const int b    = blockIdx.x;
  const int w    = (b & 7) * (n >> 3) + (b >> 3);
  const int srel = w >> 6;             // 64 m-blocks per site
  const int m0   = (w & 63) * BM;

  const f16* ap  = A  + (size_t)srel * strideAS + (size_t)m0 * Kd;
  const f16* wph = Wh + (size_t)srel * BN * Kd;
  const f16* wpl = SPLIT ? (Wl + (size_t)srel * BN * Kd) : nullptr;
  const int tid = threadIdx.x, wbase = tid & ~63;
  const int wave = tid >> 6, lane = tid & 63;
  const int wr = wave >> 2, wc = wave & 3;
  f32x4 acc[FM][FN] = {};
  const int laneRow = lane & 15;
  const int hi      = lane >> 4;

  // prologue: stage A(0) -> As0[0], Wh(0) -> Bs0[0]
  {
    const int r = tid / CPR, c = tid % CPR, cg = c ^ (r & SWZ);
    gload16(ap + (size_t)r * Kd + cg * 8, As0 + (size_t)wbase * 8);
  }
#pragma unroll
  for (int base = 0; base < BN * CPR; base += 512) {
    const int idx = base + tid;
    const int r = idx / CPR, c = idx % CPR, cg = c ^ (r & SWZ);
    gload16(wph + (size_t)r * Kd + cg * 8, Bs0 + (size_t)(base + wbase) * 8);
  }
  __syncthreads();

  const int NT = Kd / BK;
  const int NV = SPLIT ? NT * 2 : NT;   // virtual steps
  for (int v = 0; v < NV; ++v) {
    const int ktile = SPLIT ? (v >> 1) : v;
    f16* const Acur = As0 + (size_t)(ktile & 1) * BM * BK;
    f16* const Bcur = Bs0 + (size_t)(v & 1) * BN * BK;
    // ---- issue next step's staging into the OTHER buffers ----
    if (v + 1 < NV) {
      const int nk = SPLIT ? ((v + 1) >> 1) : (v + 1);
      const bool newTile = SPLIT ? (((v + 1) & 1) == 0) : true;
      if (newTile) {   // new K-tile: stage its A
        f16* const Anxt = As0 + (size_t)(nk & 1) * BM * BK;
        const int r = tid / CPR, c = tid % CPR, cg = c ^ (r & SWZ);
        gload16(ap + (size_t)r * Kd + nk * BK + cg * 8, Anxt + (size_t)wbase * 8);
      }
      const f16* src = (SPLIT && ((v + 1) & 1)) ? wpl : wph;
      f16* const Bnxt = Bs0 + (size_t)((v + 1) & 1) * BN * BK;
#pragma unroll
      for (int base = 0; base < BN * CPR; base += 512) {
        const int idx = base + tid;
        const int r = idx / CPR, c = idx % CPR, cg = c ^ (r & SWZ);
        gload16(src + (size_t)r * Kd + nk * BK + cg * 8, Bnxt + (size_t)(base + wbase) * 8);
      }
    }
    // ---- compute current: acc += A(ktile) * B(v) ----
#pragma unroll
    for (int kk = 0; kk < BK / 32; ++kk) {
      const int cc = kk * 4 + hi;
      f16x8 a[FM];
#pragma unroll
      for (int mi = 0; mi < FM; ++mi) {
        const int row = wr * WM + mi * 16 + laneRow;
        a[mi] = *reinterpret_cast<const f16x8*>(&Acur[row * BK + ((cc ^ (row & SWZ)) << 3)]);
      }
#pragma unroll
      for (int ni = 0; ni < FN; ++ni) {
        const int row = wc * WN + ni * 16 + laneRow;
        f16x8 bv = *reinterpret_cast<const f16x8*>(&Bcur[row * BK + ((cc ^ (row & SWZ)) << 3)]);
#pragma unroll
        for (int mi = 0; mi < FM; ++mi)
          acc[mi][ni] = __builtin_amdgcn_mfma_f32_16x16x32_f16(a[mi], bv, acc[mi][ni], 0, 0, 0);
      }
    }
    __syncthreads();   // readers of current bufs done; next-step loads drained
  }

  // ---------------- fused epilogue: bias(+resid) -> gelu -> LN -> f16 -------
  const int rbase = hi * 4;
  float bv[FN], sv[FN], bb[FN];
#pragma unroll
  for (int ni = 0; ni < FN; ++ni) {
    const int gn = wc * WN + ni * 16 + laneRow;
    bv[ni] = bias[srel * H + gn];
    sv[ni] = lns[srel * H + gn];
    bb[ni] = lnb[srel * H + gn];
  }
  float lsum[FM][4], lsq[FM][4];
#pragma unroll
  for (int mi = 0; mi < FM; ++mi)
#pragma unroll
    for (int r = 0; r < 4; ++r) { lsum[mi][r] = 0.f; lsq[mi][r] = 0.f; }
#pragma unroll
  for (int mi = 0; mi < FM; ++mi)
#pragma unroll
    for (int r = 0; r < 4; ++r) {
      const int row = wr * WM + mi * 16 + rbase + r;
#pragma unroll
      for (int ni = 0; ni < FN; ++ni) {
        const int gn = wc * WN + ni * 16 + laneRow;
        float y = acc[mi][ni][r] + bv[ni];
        if constexpr (RES)
          y += (float)A[(size_t)srel * strideAS + (size_t)(m0 + row) * Kd + gn];
        float g = gelu_tanh(y);
        acc[mi][ni][r] = g;
        lsum[mi][r] += g;
        lsq[mi][r]  += g * g;
      }
    }
#pragma unroll
  for (int o = 1; o < 16; o <<= 1)
#pragma unroll
    for (int mi = 0; mi < FM; ++mi)
#pragma unroll
      for (int r = 0; r < 4; ++r) {
        lsum[mi][r] += __shfl_xor(lsum[mi][r], o, 64);
        lsq[mi][r]  += __shfl_xor(lsq[mi][r], o, 64);
      }
  __syncthreads();                       // all waves past K-loop LDS reads
  float* red = reinterpret_cast<float*>(smem);   // [64 rows][4 wc][2]
  if (laneRow == 0) {
#pragma unroll
    for (int mi = 0; mi < FM; ++mi)
#pragma unroll
      for (int r = 0; r < 4; ++r) {
        const int row = wr * WM + mi * 16 + rbase + r;
        red[(row * 4 + wc) * 2 + 0] = lsum[mi][r];
        red[(row * 4 + wc) * 2 + 1] = lsq[mi][r];
      }
  }
  __syncthreads();
#pragma unroll
  for (int mi = 0; mi < FM; ++mi)
#pragma unroll
    for (int r = 0; r < 4; ++r) {
      const int row = wr * WM + mi * 16 + rbase + r;
      float sum = 0.f, sq = 0.f;
#pragma unroll
      for (int w4 = 0; w4 < 4; ++w4) {
        sum += red[(row * 4 + w4) * 2 + 0];
        sq  += red[(row * 4 + w4) * 2 + 1];
      }
      const float mean = sum * (1.f / 512.f);
      const float var  = sq * (1.f / 512.f) - mean * mean;
      const float rstd = 1.f / sqrtf(var + 1e-6f);
#pragma unroll
      for (int ni = 0; ni < FN; ++ni) {
        const int gn = wc * WN + ni * 16 + laneRow;
        float z = (acc[mi][ni][r] - mean) * rstd * sv[ni] + bb[ni];
        out[((size_t)srel * M + m0 + row) * H + gn] = (f16)z;
      }
    }
}

// ---- final projection GEMM, W-split f16 (2 MFMA), f32 out -------------------
__global__ __launch_bounds__(512) void gemm_out_kernel(
    const f16* __restrict__ A, const f16* __restrict__ Wh, const f16* __restrict__ Wl,
    const float* __restrict__ bias, float* __restrict__ out,
    int M, int Kd, int strideAS) {
  constexpr int BM = 128, BN = 112, BK = 64;
  constexpr int CPR = BK / 8, SWZ = CPR - 1;
  constexpr int FN = 7;
  extern __shared__ f16 smem[];
  f16* As  = smem;               // 128*64
  f16* Bhs = As + BM * BK;       // 112*64
  f16* Bls = Bhs + BN * BK;

  const int s  = blockIdx.z;
  const int m0 = blockIdx.x * BM;
  const f16* ap  = A  + (size_t)s * strideAS + (size_t)m0 * Kd;
  const f16* wph = Wh + (size_t)s * BN * Kd;
  const f16* wpl = Wl + (size_t)s * BN * Kd;
  const int tid = threadIdx.x, wbase = tid & ~63;
  const int wave = tid >> 6, lane = tid & 63;
  const int wr = wave;           // 16 rows per wave
  f32x4 acc[FN] = {};
  const int laneRow = lane & 15;
  const int hi      = lane >> 4;

  for (int k0 = 0; k0 < Kd; k0 += BK) {
    __syncthreads();
#pragma unroll
    for (int base = 0; base < BM * CPR; base += 512) {   // 1024 chunks
      const int idx = base + tid;
      const int r = idx / CPR, c = idx % CPR, cg = c ^ (r & SWZ);
      gload16(ap + (size_t)r * Kd + k0 + cg * 8, As + (size_t)(base + wbase) * 8);
    }
#pragma unroll
    for (int base = 0; base < BN * CPR; base += 512) {   // 896 chunks, partial
      const int idx = base + tid;
      if (idx < BN * CPR) {
        const int r = idx / CPR, c = idx % CPR, cg = c ^ (r & SWZ);
        const size_t go = (size_t)r * Kd + k0 + cg * 8;
        gload16(wph + go, Bhs + (size_t)(base + wbase) * 8);
        gload16(wpl + go, Bls + (size_t)(base + wbase) * 8);
      }
    }
    __syncthreads();
#pragma unroll
    for (int kk = 0; kk < BK / 32; ++kk) {
      const int cc = kk * 4 + hi;
      const int rowA = wr * 16 + laneRow;
      f16x8 a = *reinterpret_cast<const f16x8*>(&As[rowA * BK + ((cc ^ (rowA & SWZ)) << 3)]);
#pragma unroll
      for (int ni = 0; ni < FN; ++ni) {
        const int row = ni * 16 + laneRow;
        const int off = row * BK + ((cc ^ (row & SWZ)) << 3);
        f16x8 bh = *reinterpret_cast<const f16x8*>(&Bhs[off]);
        f16x8 bl = *reinterpret_cast<const f16x8*>(&Bls[off]);
        acc[ni] = __builtin_amdgcn_mfma_f32_16x16x32_f16(a, bh, acc[ni], 0, 0, 0);
        acc[ni] = __builtin_amdgcn_mfma_f32_16x16x32_f16(a, bl, acc[ni], 0, 0, 0);
      }
    }
  }

  const int rbase = hi * 4;
#pragma unroll
  for (int ni = 0; ni < FN; ++ni)
#pragma unroll
    for (int r = 0; r < 4; ++r) {
      const int gm = m0 + wr * 16 + rbase + r;
      const int gn = ni * 16 + laneRow;
      if (gn < OUTC)
        out[((size_t)s * M + gm) * OUTC + gn] = acc[ni][r] + bias[s * OUTC + gn];
    }
}

// ---------------- RQS spline: one thread per (b,i), params via LDS -----------
DI float invsymlu(float u) { return u >= 0.f ? u + 1.f : 1.f / (1.f - u); }

__global__ __launch_bounds__(128) void spline_kernel(
    const float* __restrict__ x, const float* __restrict__ bias0,
    const float* __restrict__ p, float* __restrict__ out0, float* __restrict__ ladbuf) {
  __shared__ float prm[128 * 101];   // stride 101: conflict-free
  const int i  = blockIdx.x;         // 0..15
  const int b0 = blockIdx.y * 128;
  if (i == 0) {
    for (int idx = threadIdx.x; idx < 128 * OUTC; idx += 128)
      prm[(idx / OUTC) * 101 + idx % OUTC] = bias0[idx % OUTC];
  } else {
    const float* src = p + ((size_t)(i - 1) * BATCH + b0) * OUTC;
    for (int idx = threadIdx.x; idx < 128 * OUTC; idx += 128)
      prm[(idx / OUTC) * 101 + idx % OUTC] = src[idx];
  }
  __syncthreads();
  const float* P = &prm[threadIdx.x * 101];
  const int b = b0 + threadIdx.x;
  const float inp = x[b * 16 + i];

  float tw = 0.f, th = 0.f;
  for (int k = 0; k < 32; ++k) tw += 0.001f + invsymlu(P[k]);
  for (int k = 0; k < 32; ++k) th += 0.001f + invsymlu(P[32 + k]);
  const float cx = P[97], cy = P[98];
  const float w0 = cx - 0.5f * tw, wK = cx + 0.5f * tw;
  const float h0 = cy - 0.5f * th, hK = cy + 0.5f * th;
  const float d0 = 0.001f + invsymlu(P[64]);
  const float dK = 0.001f + invsymlu(P[96]);
  float outv, lad;
  if (inp < w0) {
    outv = h0 - (w0 - inp) * d0;
    lad  = logf(d0);
  } else if (inp >= wK) {
    outv = (inp - wK) * dK + hK;
    lad  = logf(dK);
  } else {
    float run = w0, icw = w0, ibw = 1.f;
    int bin = 0;
    for (int k = 0; k < 32; ++k) {
      float wk = 0.001f + invsymlu(P[k]);
      if (inp >= run) { bin = k; icw = run; ibw = wk; }
      run += wk;
    }
    float runh = h0;
    for (int k = 0; k < bin; ++k) runh += 0.001f + invsymlu(P[32 + k]);
    const float ih    = 0.001f + invsymlu(P[32 + bin]);
    const float ich   = runh;
    const float ider  = 0.001f + invsymlu(P[64 + bin]);
    const float iderp = 0.001f + invsymlu(P[64 + bin + 1]);
    const float idl   = ih / ibw;
    const float theta = (inp - icw) / ibw;
    const float omt   = 1.f - theta;
    const float tomt  = theta * omt;
    const float num   = ih * (idl * theta * theta + ider * tomt);
    const float den   = idl + (ider + iderp - 2.f * idl) * tomt;
    outv = ich + num / den;
    const float dnum = idl * idl * (iderp * theta * theta + 2.f * idl * tomt + ider * omt * omt);
    lad = logf(dnum) - 2.f * logf(den);
  }
  out0[b * 16 + i]   = outv;
  ladbuf[b * 16 + i] = lad;
}

__global__ void lad_reduce_kernel(const float* __restrict__ ladbuf, float* __restrict__ out1) {
  const int b = blockIdx.x * 256 + threadIdx.x;
  float s = 0.f;
#pragma unroll
  for (int i = 0; i < 16; ++i) s += ladbuf[b * 16 + i];
  out1[b] = s;
}

// ---------------------------------------------------------------------------
extern "C" void kernel_launch(void* const* d_in, const int* in_sizes, int n_in,
                              void* d_out, int out_size, void* d_ws, size_t ws_size,
                              hipStream_t stream) {
  const float* x     = (const float*)d_in[0];
  const float* bias0 = (const float*)d_in[1];
  const float* W0    = (const float*)d_in[2];
  const float* b0    = (const float*)d_in[3];
  const float* ln0s  = (const float*)d_in[4];
  const float* ln0b  = (const float*)d_in[5];
  const float* W1    = (const float*)d_in[6];
  const float* b1    = (const float*)d_in[7];
  const float* ln1s  = (const float*)d_in[8];
  const float* ln1b  = (const float*)d_in[9];
  const float* W2    = (const float*)d_in[10];
  const float* b2    = (const float*)d_in[11];
  const float* ln2s  = (const float*)d_in[12];
  const float* ln2b  = (const float*)d_in[13];
  const float* Wf    = (const float*)d_in[14];
  const float* bfb   = (const float*)d_in[15];
  float* out0 = (float*)d_out;
  float* out1 = out0 + BATCH * 16;

  // ---- workspace budget ----------------------------------------------------
  const size_t fixedBytes =
      (size_t)BATCH * DPAD * 2 +                // e
      2 * ((size_t)S1 * H * DPAD * 2) +         // W0T h,l
      2 * ((size_t)S1 * H * H * 2) +            // W1T h + W2T h (single)
      2 * ((size_t)S1 * OUTPAD * H * 2) +       // WfT h,l
      (size_t)S1 * BATCH * OUTC * 4 +           // pbuf
      (size_t)BATCH * 16 * 4 +                  // ladb
      64 * 256;
  const size_t perSiteP = 2 * ((size_t)BATCH * H * 2);  // P1+P2 per site
  int CH = 1;
  if (ws_size > fixedBytes) {
    size_t c = (ws_size - fixedBytes) / perSiteP;
    CH = (c >= (size_t)S1) ? S1 : (c < 1 ? 1 : (int)c);
  }
  const int nPasses = (S1 + CH - 1) / CH;
  const int baseSz  = S1 / nPasses;
  const int remSz   = S1 % nPasses;

  char* ws = (char*)d_ws;
  size_t off = 0;
  auto take = [&](size_t bytes) {
    char* q = ws + off;
    off += (bytes + 255) & ~(size_t)255;
    return q;
  };
  f16* e     = (f16*)take((size_t)BATCH * DPAD * 2);
  f16* W0Th  = (f16*)take((size_t)S1 * H * DPAD * 2);
  f16* W0Tl  = (f16*)take((size_t)S1 * H * DPAD * 2);
  f16* W1Th  = (f16*)take((size_t)S1 * H * H * 2);   // single-f16
  f16* W2Th  = (f16*)take((size_t)S1 * H * H * 2);   // single-f16
  f16* WfTh  = (f16*)take((size_t)S1 * OUTPAD * H * 2);
  f16* WfTl  = (f16*)take((size_t)S1 * OUTPAD * H * 2);
  f16* P1    = (f16*)take((size_t)CH * BATCH * H * 2);
  f16* P2    = (f16*)take((size_t)CH * BATCH * H * 2);
  float* pbuf = (float*)take((size_t)S1 * BATCH * OUTC * 4);
  float* ladb = (float*)take((size_t)BATCH * 16 * 4);

  embed_kernel<<<BATCH, 128, 0, stream>>>(x, e);
  transpose_conv_kernel<<<dim3(4, 16, S1), 256, 0, stream>>>(W0, W0Th, W0Tl, 120, H, DPAD, H, 8);
  transpose_conv_kernel<<<dim3(16, 16, S1), 256, 0, stream>>>(W1, W1Th, nullptr, H, H, H, H, 0);
  transpose_conv_kernel<<<dim3(16, 16, S1), 256, 0, stream>>>(W2, W2Th, nullptr, H, H, H, H, 0);
  transpose_conv_kernel<<<dim3(16, 4, S1), 256, 0, stream>>>(Wf, WfTh, WfTl, H, OUTC, H, OUTPAD, 0);

  const size_t ldsFused = (size_t)(2 * 64 + 2 * 512) * 64 * 2;   // 147456 B
  const size_t ldsOut   = (size_t)(128 + 112 + 112) * 64 * 2;    // 45056 B

  int sb = 0;
  for (int pass = 0; pass < nPasses; ++pass) {
    const int nz = baseSz + (pass < remSz ? 1 : 0);
    const int gridFused = (BATCH / 64) * nz;   // 64*nz, %8==0
    // layer 0: e (shared) -> P2  [fused gelu+LN, W-split]
    gemm_ln_kernel<false, true><<<gridFused, 512, ldsFused, stream>>>(
        e, W0Th + (size_t)sb * H * DPAD, W0Tl + (size_t)sb * H * DPAD,
        b0 + sb * H, ln0s + sb * H, ln0b + sb * H, P2, BATCH, DPAD, 0);
    // layer 1: P2 -> P1 (residual = P2)  [fused, single-f16 W1]
    gemm_ln_kernel<true, false><<<gridFused, 512, ldsFused, stream>>>(
        P2, W1Th + (size_t)sb * H * H, nullptr,
        b1 + sb * H, ln1s + sb * H, ln1b + sb * H, P1, BATCH, H, BATCH * H);
    // layer 2: P1 -> P2 (residual = P1)  [fused, single-f16 W2]
    gemm_ln_kernel<true, false><<<gridFused, 512, ldsFused, stream>>>(
        P1, W2Th + (size_t)sb * H * H, nullptr,
        b2 + sb * H, ln2s + sb * H, ln2b + sb * H, P2, BATCH, H, BATCH * H);
    // final projection: P2 -> pbuf (f32)
    gemm_out_kernel<<<dim3(BATCH / 128, 1, nz), 512, ldsOut, stream>>>(
        P2, WfTh + (size_t)sb * OUTPAD * H, WfTl + (size_t)sb * OUTPAD * H,
        bfb + sb * OUTC, pbuf + (size_t)sb * BATCH * OUTC, BATCH, H, BATCH * H);
    sb += nz;
  }

  spline_kernel<<<dim3(16, 32), 128, 0, stream>>>(x, bias0, pbuf, out0, ladb);
  lad_reduce_kernel<<<BATCH / 256, 256, 0, stream>>>(ladb, out1);
}

// Round 25
// 292.686 us; speedup vs baseline: 1.3136x; 1.0030x over previous
//
#include <hip/hip_runtime.h>
#include <hip/hip_bf16.h>
#include <cstdint>
#include <cstddef>

typedef _Float16 f16;
typedef __attribute__((ext_vector_type(8))) _Float16 f16x8;   // MFMA A/B frag
typedef __attribute__((ext_vector_type(4))) float f32x4;      // MFMA C/D frag

#define DI __device__ __forceinline__

constexpr int BATCH  = 4096;
constexpr int S1     = 15;
constexpr int DPAD   = 128;   // 120 padded to 128
constexpr int H      = 512;
constexpr int OUTC   = 99;
constexpr int OUTPAD = 112;   // 99 padded to 7*16

// jax.nn.gelu (tanh approx) = x * sigmoid(2*0.79788456*(x+0.044715x^3)).
DI float gelu_tanh(float x) {
  float t = 1.5957691216057308f * (x + 0.044715f * x * x * x);
  return x / (1.f + __expf(-t));
}

// async 16B global -> LDS (wave-uniform LDS base + lane*16)
DI void gload16(const void* g, void* l) {
  __builtin_amdgcn_global_load_lds(
      (const __attribute__((address_space(1))) void*)g,
      (__attribute__((address_space(3))) void*)l, 16, 0, 0);
}

// ---------------- embeddings: e[b][d] f16, d in [0,128), pad zeros -----------
__global__ void embed_kernel(const float* __restrict__ x, f16* __restrict__ e) {
  const int b = blockIdx.x, d = threadIdx.x;  // 128 threads
  float v = 0.f;
  if (d < 120) {
    const float divs[4] = {1.f, 0.31622776601683794f, 0.1f, 0.03162277660168379f};
    int site = d >> 3, j = d & 7;
    float arg = x[b * 16 + site] * divs[j & 3];
    v = (j < 4) ? sinf(arg) : cosf(arg);
  }
  e[b * DPAD + d] = (f16)v;
}

// ---- transpose+convert: dst[s][n][k] = f16(src[s][k][n]) (optional lo part) -
__global__ __launch_bounds__(256) void transpose_conv_kernel(
    const float* __restrict__ src, f16* __restrict__ dsth, f16* __restrict__ dstl,
    int K, int N, int Kpad, int Npad, int maskMul) {
  __shared__ float tile[32][33];
  const int s  = blockIdx.z;
  const int kb = blockIdx.x * 32, nb = blockIdx.y * 32;
  const int tx = threadIdx.x & 31, ty = threadIdx.x >> 5;  // 32 x 8
  for (int i = ty; i < 32; i += 8) {
    int k = kb + i, n = nb + tx;
    tile[i][tx] = (k < K && n < N) ? src[((size_t)s * K + k) * N + n] : 0.f;
  }
  __syncthreads();
  const int klim = maskMul ? maskMul * (s + 1) : 0x7FFFFFFF;
  for (int i = ty; i < 32; i += 8) {
    int n = nb + i, k = kb + tx;
    if (n < Npad && k < Kpad) {
      float v = (k < klim) ? tile[tx][i] : 0.f;
      size_t o = ((size_t)s * Npad + n) * Kpad + k;
      f16 h = (f16)v;
      dsth[o] = h;
      if (dstl) dstl[o] = (f16)(v - (float)h);
    }
  }
}

// ---- fused GEMM + gelu + LayerNorm, optional W-split, 2-phase pipeline ------
// R25 = exact revert to R23 (proven: 293.6us, absmax 0.28125). Error ledger
// (R22-R24 measured): W1/W2 splits worth ~0; W0+Wf splits load-bearing
// (dropping both -> 0.875 fail). R23 is the precision/speed knee.
// BM=64, BN=512, BK=64, 512 threads (8 waves 2mx4n), WM=32, WN=128.
// LDS 144KB = A-dbuf 2x8K + B-dbuf 2x64K. Each step: ISSUE next step's
// global_load_lds into the other buffer FIRST, then MFMA current, then one
// barrier. XCD swizzle: grid = 64*nz (%8==0); w=(b&7)*(n/8)+(b>>3).
template<bool RES, bool SPLIT>
__global__ __launch_bounds__(512) void gemm_ln_kernel(
    const f16* __restrict__ A, const f16* __restrict__ Wh, const f16* __restrict__ Wl,
    const float* __restrict__ bias, const float* __restrict__ lns,
    const float* __restrict__ lnb, f16* __restrict__ out,
    int M, int Kd, int strideAS) {
  constexpr int BM = 64, BN = 512, BK = 64;
  constexpr int CPR = BK / 8, SWZ = CPR - 1;
  constexpr int WM = 32, WN = 128, FM = 2, FN = 8;
  extern __shared__ f16 smem[];
  f16* const As0 = smem;                 // [2][BM*BK]  16KB
  f16* const Bs0 = smem + 2 * BM * BK;   // [2][BN*BK] 128KB

  const int n    = gridDim.x;
  const int b    = blockIdx.x;
  const int w    = (b & 7) * (n >> 3) + (b >> 3);
  const int srel = w >> 6;             // 64 m-blocks per site
  const int m0   = (w & 63) * BM;

  const f16* ap  = A  + (size_t)srel * strideAS + (size_t)m0 * Kd;
  const f16* wph = Wh + (size_t)srel * BN * Kd;
  const f16* wpl = SPLIT ? (Wl + (size_t)srel * BN * Kd) : nullptr;
  const int tid = threadIdx.x, wbase = tid & ~63;
  const int wave = tid >> 6, lane = tid & 63;
  const int wr = wave >> 2, wc = wave & 3;
  f32x4 acc[FM][FN] = {};
  const int laneRow = lane & 15;
  const int hi      = lane >> 4;

  // prologue: stage A(0) -> As0[0], Wh(0) -> Bs0[0]
  {
    const int r = tid / CPR, c = tid % CPR, cg = c ^ (r & SWZ);
    gload16(ap + (size_t)r * Kd + cg * 8, As0 + (size_t)wbase * 8);
  }
#pragma unroll
  for (int base = 0; base < BN * CPR; base += 512) {
    const int idx = base + tid;
    const int r = idx / CPR, c = idx % CPR, cg = c ^ (r & SWZ);
    gload16(wph + (size_t)r * Kd + cg * 8, Bs0 + (size_t)(base + wbase) * 8);
  }
  __syncthreads();

  const int NT = Kd / BK;
  const int NV = SPLIT ? NT * 2 : NT;   // virtual steps
  for (int v = 0; v < NV; ++v) {
    const int ktile = SPLIT ? (v >> 1) : v;
    f16* const Acur = As0 + (size_t)(ktile & 1) * BM * BK;
    f16* const Bcur = Bs0 + (size_t)(v & 1) * BN * BK;
    // ---- issue next step's staging into the OTHER buffers ----
    if (v + 1 < NV) {
      const int nk = SPLIT ? ((v + 1) >> 1) : (v + 1);
      const bool newTile = SPLIT ? (((v + 1) & 1) == 0) : true;
      if (newTile) {   // new K-tile: stage its A
        f16* const Anxt = As0 + (size_t)(nk & 1) * BM * BK;
        const int r = tid / CPR, c = tid % CPR, cg = c ^ (r & SWZ);
        gload16(ap + (size_t)r * Kd + nk * BK + cg * 8, Anxt + (size_t)wbase * 8);
      }
      const f16* src = (SPLIT && ((v + 1) & 1)) ? wpl : wph;
      f16* const Bnxt = Bs0 + (size_t)((v + 1) & 1) * BN * BK;
#pragma unroll
      for (int base = 0; base < BN * CPR; base += 512) {
        const int idx = base + tid;
        const int r = idx / CPR, c = idx % CPR, cg = c ^ (r & SWZ);
        gload16(src + (size_t)r * Kd + nk * BK + cg * 8, Bnxt + (size_t)(base + wbase) * 8);
      }
    }
    // ---- compute current: acc += A(ktile) * B(v) ----
#pragma unroll
    for (int kk = 0; kk < BK / 32; ++kk) {
      const int cc = kk * 4 + hi;
      f16x8 a[FM];
#pragma unroll
      for (int mi = 0; mi < FM; ++mi) {
        const int row = wr * WM + mi * 16 + laneRow;
        a[mi] = *reinterpret_cast<const f16x8*>(&Acur[row * BK + ((cc ^ (row & SWZ)) << 3)]);
      }
#pragma unroll
      for (int ni = 0; ni < FN; ++ni) {
        const int row = wc * WN + ni * 16 + laneRow;
        f16x8 bv = *reinterpret_cast<const f16x8*>(&Bcur[row * BK + ((cc ^ (row & SWZ)) << 3)]);
#pragma unroll
        for (int mi = 0; mi < FM; ++mi)
          acc[mi][ni] = __builtin_amdgcn_mfma_f32_16x16x32_f16(a[mi], bv, acc[mi][ni], 0, 0, 0);
      }
    }
    __syncthreads();   // readers of current bufs done; next-step loads drained
  }

  // ---------------- fused epilogue: bias(+resid) -> gelu -> LN -> f16 -------
  const int rbase = hi * 4;
  float bv[FN], sv[FN], bb[FN];
#pragma unroll
  for (int ni = 0; ni < FN; ++ni) {
    const int gn = wc * WN + ni * 16 + laneRow;
    bv[ni] = bias[srel * H + gn];
    sv[ni] = lns[srel * H + gn];
    bb[ni] = lnb[srel * H + gn];
  }
  float lsum[FM][4], lsq[FM][4];
#pragma unroll
  for (int mi = 0; mi < FM; ++mi)
#pragma unroll
    for (int r = 0; r < 4; ++r) { lsum[mi][r] = 0.f; lsq[mi][r] = 0.f; }
#pragma unroll
  for (int mi = 0; mi < FM; ++mi)
#pragma unroll
    for (int r = 0; r < 4; ++r) {
      const int row = wr * WM + mi * 16 + rbase + r;
#pragma unroll
      for (int ni = 0; ni < FN; ++ni) {
        const int gn = wc * WN + ni * 16 + laneRow;
        float y = acc[mi][ni][r] + bv[ni];
        if constexpr (RES)
          y += (float)A[(size_t)srel * strideAS + (size_t)(m0 + row) * Kd + gn];
        float g = gelu_tanh(y);
        acc[mi][ni][r] = g;
        lsum[mi][r] += g;
        lsq[mi][r]  += g * g;
      }
    }
#pragma unroll
  for (int o = 1; o < 16; o <<= 1)
#pragma unroll
    for (int mi = 0; mi < FM; ++mi)
#pragma unroll
      for (int r = 0; r < 4; ++r) {
        lsum[mi][r] += __shfl_xor(lsum[mi][r], o, 64);
        lsq[mi][r]  += __shfl_xor(lsq[mi][r], o, 64);
      }
  __syncthreads();                       // all waves past K-loop LDS reads
  float* red = reinterpret_cast<float*>(smem);   // [64 rows][4 wc][2]
  if (laneRow == 0) {
#pragma unroll
    for (int mi = 0; mi < FM; ++mi)
#pragma unroll
      for (int r = 0; r < 4; ++r) {
        const int row = wr * WM + mi * 16 + rbase + r;
        red[(row * 4 + wc) * 2 + 0] = lsum[mi][r];
        red[(row * 4 + wc) * 2 + 1] = lsq[mi][r];
      }
  }
  __syncthreads();
#pragma unroll
  for (int mi = 0; mi < FM; ++mi)
#pragma unroll
    for (int r = 0; r < 4; ++r) {
      const int row = wr * WM + mi * 16 + rbase + r;
      float sum = 0.f, sq = 0.f;
#pragma unroll
      for (int w4 = 0; w4 < 4; ++w4) {
        sum += red[(row * 4 + w4) * 2 + 0];
        sq  += red[(row * 4 + w4) * 2 + 1];
      }
      const float mean = sum * (1.f / 512.f);
      const float var  = sq * (1.f / 512.f) - mean * mean;
      const float rstd = 1.f / sqrtf(var + 1e-6f);
#pragma unroll
      for (int ni = 0; ni < FN; ++ni) {
        const int gn = wc * WN + ni * 16 + laneRow;
        float z = (acc[mi][ni][r] - mean) * rstd * sv[ni] + bb[ni];
        out[((size_t)srel * M + m0 + row) * H + gn] = (f16)z;
      }
    }
}

// ---- final projection GEMM, W-split f16 (2 MFMA), f32 out -------------------
__global__ __launch_bounds__(512) void gemm_out_kernel(
    const f16* __restrict__ A, const f16* __restrict__ Wh, const f16* __restrict__ Wl,
    const float* __restrict__ bias, float* __restrict__ out,
    int M, int Kd, int strideAS) {
  constexpr int BM = 128, BN = 112, BK = 64;
  constexpr int CPR = BK / 8, SWZ = CPR - 1;
  constexpr int FN = 7;
  extern __shared__ f16 smem[];
  f16* As  = smem;               // 128*64
  f16* Bhs = As + BM * BK;       // 112*64
  f16* Bls = Bhs + BN * BK;

  const int s  = blockIdx.z;
  const int m0 = blockIdx.x * BM;
  const f16* ap  = A  + (size_t)s * strideAS + (size_t)m0 * Kd;
  const f16* wph = Wh + (size_t)s * BN * Kd;
  const f16* wpl = Wl + (size_t)s * BN * Kd;
  const int tid = threadIdx.x, wbase = tid & ~63;
  const int wave = tid >> 6, lane = tid & 63;
  const int wr = wave;           // 16 rows per wave
  f32x4 acc[FN] = {};
  const int laneRow = lane & 15;
  const int hi      = lane >> 4;

  for (int k0 = 0; k0 < Kd; k0 += BK) {
    __syncthreads();
#pragma unroll
    for (int base = 0; base < BM * CPR; base += 512) {   // 1024 chunks
      const int idx = base + tid;
      const int r = idx / CPR, c = idx % CPR, cg = c ^ (r & SWZ);
      gload16(ap + (size_t)r * Kd + k0 + cg * 8, As + (size_t)(base + wbase) * 8);
    }
#pragma unroll
    for (int base = 0; base < BN * CPR; base += 512) {   // 896 chunks, partial
      const int idx = base + tid;
      if (idx < BN * CPR) {
        const int r = idx / CPR, c = idx % CPR, cg = c ^ (r & SWZ);
        const size_t go = (size_t)r * Kd + k0 + cg * 8;
        gload16(wph + go, Bhs + (size_t)(base + wbase) * 8);
        gload16(wpl + go, Bls + (size_t)(base + wbase) * 8);
      }
    }
    __syncthreads();
#pragma unroll
    for (int kk = 0; kk < BK / 32; ++kk) {
      const int cc = kk * 4 + hi;
      const int rowA = wr * 16 + laneRow;
      f16x8 a = *reinterpret_cast<const f16x8*>(&As[rowA * BK + ((cc ^ (rowA & SWZ)) << 3)]);
#pragma unroll
      for (int ni = 0; ni < FN; ++ni) {
        const int row = ni * 16 + laneRow;
        const int off = row * BK + ((cc ^ (row & SWZ)) << 3);
        f16x8 bh = *reinterpret_cast<const f16x8*>(&Bhs[off]);
        f16x8 bl = *reinterpret_cast<const f16x8*>(&Bls[off]);
        acc[ni] = __builtin_amdgcn_mfma_f32_16x16x32_f16(a, bh, acc[ni], 0, 0, 0);
        acc[ni] = __builtin_amdgcn_mfma_f32_16x16x32_f16(a, bl, acc[ni], 0, 0, 0);
      }
    }
  }

  const int rbase = hi * 4;
#pragma unroll
  for (int ni = 0; ni < FN; ++ni)
#pragma unroll
    for (int r = 0; r < 4; ++r) {
      const int gm = m0 + wr * 16 + rbase + r;
      const int gn = ni * 16 + laneRow;
      if (gn < OUTC)
        out[((size_t)s * M + gm) * OUTC + gn] = acc[ni][r] + bias[s * OUTC + gn];
    }
}

// ---------------- RQS spline: one thread per (b,i), params via LDS -----------
DI float invsymlu(float u) { return u >= 0.f ? u + 1.f : 1.f / (1.f - u); }

__global__ __launch_bounds__(128) void spline_kernel(
    const float* __restrict__ x, const float* __restrict__ bias0,
    const float* __restrict__ p, float* __restrict__ out0, float* __restrict__ ladbuf) {
  __shared__ float prm[128 * 101];   // stride 101: conflict-free
  const int i  = blockIdx.x;         // 0..15
  const int b0 = blockIdx.y * 128;
  if (i == 0) {
    for (int idx = threadIdx.x; idx < 128 * OUTC; idx += 128)
      prm[(idx / OUTC) * 101 + idx % OUTC] = bias0[idx % OUTC];
  } else {
    const float* src = p + ((size_t)(i - 1) * BATCH + b0) * OUTC;
    for (int idx = threadIdx.x; idx < 128 * OUTC; idx += 128)
      prm[(idx / OUTC) * 101 + idx % OUTC] = src[idx];
  }
  __syncthreads();
  const float* P = &prm[threadIdx.x * 101];
  const int b = b0 + threadIdx.x;
  const float inp = x[b * 16 + i];

  float tw = 0.f, th = 0.f;
  for (int k = 0; k < 32; ++k) tw += 0.001f + invsymlu(P[k]);
  for (int k = 0; k < 32; ++k) th += 0.001f + invsymlu(P[32 + k]);
  const float cx = P[97], cy = P[98];
  const float w0 = cx - 0.5f * tw, wK = cx + 0.5f * tw;
  const float h0 = cy - 0.5f * th, hK = cy + 0.5f * th;
  const float d0 = 0.001f + invsymlu(P[64]);
  const float dK = 0.001f + invsymlu(P[96]);
  float outv, lad;
  if (inp < w0) {
    outv = h0 - (w0 - inp) * d0;
    lad  = logf(d0);
  } else if (inp >= wK) {
    outv = (inp - wK) * dK + hK;
    lad  = logf(dK);
  } else {
    float run = w0, icw = w0, ibw = 1.f;
    int bin = 0;
    for (int k = 0; k < 32; ++k) {
      float wk = 0.001f + invsymlu(P[k]);
      if (inp >= run) { bin = k; icw = run; ibw = wk; }
      run += wk;
    }
    float runh = h0;
    for (int k = 0; k < bin; ++k) runh += 0.001f + invsymlu(P[32 + k]);
    const float ih    = 0.001f + invsymlu(P[32 + bin]);
    const float ich   = runh;
    const float ider  = 0.001f + invsymlu(P[64 + bin]);
    const float iderp = 0.001f + invsymlu(P[64 + bin + 1]);
    const float idl   = ih / ibw;
    const float theta = (inp - icw) / ibw;
    const float omt   = 1.f - theta;
    const float tomt  = theta * omt;
    const float num   = ih * (idl * theta * theta + ider * tomt);
    const float den   = idl + (ider + iderp - 2.f * idl) * tomt;
    outv = ich + num / den;
    const float dnum = idl * idl * (iderp * theta * theta + 2.f * idl * tomt + ider * omt * omt);
    lad = logf(dnum) - 2.f * logf(den);
  }
  out0[b * 16 + i]   = outv;
  ladbuf[b * 16 + i] = lad;
}

__global__ void lad_reduce_kernel(const float* __restrict__ ladbuf, float* __restrict__ out1) {
  const int b = blockIdx.x * 256 + threadIdx.x;
  float s = 0.f;
#pragma unroll
  for (int i = 0; i < 16; ++i) s += ladbuf[b * 16 + i];
  out1[b] = s;
}

// ---------------------------------------------------------------------------
extern "C" void kernel_launch(void* const* d_in, const int* in_sizes, int n_in,
                              void* d_out, int out_size, void* d_ws, size_t ws_size,
                              hipStream_t stream) {
  const float* x     = (const float*)d_in[0];
  const float* bias0 = (const float*)d_in[1];
  const float* W0    = (const float*)d_in[2];
  const float* b0    = (const float*)d_in[3];
  const float* ln0s  = (const float*)d_in[4];
  const float* ln0b  = (const float*)d_in[5];
  const float* W1    = (const float*)d_in[6];
  const float* b1    = (const float*)d_in[7];
  const float* ln1s  = (const float*)d_in[8];
  const float* ln1b  = (const float*)d_in[9];
  const float* W2    = (const float*)d_in[10];
  const float* b2    = (const float*)d_in[11];
  const float* ln2s  = (const float*)d_in[12];
  const float* ln2b  = (const float*)d_in[13];
  const float* Wf    = (const float*)d_in[14];
  const float* bfb   = (const float*)d_in[15];
  float* out0 = (float*)d_out;
  float* out1 = out0 + BATCH * 16;

  // ---- workspace budget ----------------------------------------------------
  const size_t fixedBytes =
      (size_t)BATCH * DPAD * 2 +                // e
      2 * ((size_t)S1 * H * DPAD * 2) +         // W0T h,l
      2 * ((size_t)S1 * H * H * 2) +            // W1T h + W2T h (single)
      2 * ((size_t)S1 * OUTPAD * H * 2) +       // WfT h,l
      (size_t)S1 * BATCH * OUTC * 4 +           // pbuf
      (size_t)BATCH * 16 * 4 +                  // ladb
      64 * 256;
  const size_t perSiteP = 2 * ((size_t)BATCH * H * 2);  // P1+P2 per site
  int CH = 1;
  if (ws_size > fixedBytes) {
    size_t c = (ws_size - fixedBytes) / perSiteP;
    CH = (c >= (size_t)S1) ? S1 : (c < 1 ? 1 : (int)c);
  }
  const int nPasses = (S1 + CH - 1) / CH;
  const int baseSz  = S1 / nPasses;
  const int remSz   = S1 % nPasses;

  char* ws = (char*)d_ws;
  size_t off = 0;
  auto take = [&](size_t bytes) {
    char* q = ws + off;
    off += (bytes + 255) & ~(size_t)255;
    return q;
  };
  f16* e     = (f16*)take((size_t)BATCH * DPAD * 2);
  f16* W0Th  = (f16*)take((size_t)S1 * H * DPAD * 2);
  f16* W0Tl  = (f16*)take((size_t)S1 * H * DPAD * 2);
  f16* W1Th  = (f16*)take((size_t)S1 * H * H * 2);   // single-f16
  f16* W2Th  = (f16*)take((size_t)S1 * H * H * 2);   // single-f16
  f16* WfTh  = (f16*)take((size_t)S1 * OUTPAD * H * 2);
  f16* WfTl  = (f16*)take((size_t)S1 * OUTPAD * H * 2);
  f16* P1    = (f16*)take((size_t)CH * BATCH * H * 2);
  f16* P2    = (f16*)take((size_t)CH * BATCH * H * 2);
  float* pbuf = (float*)take((size_t)S1 * BATCH * OUTC * 4);
  float* ladb = (float*)take((size_t)BATCH * 16 * 4);

  embed_kernel<<<BATCH, 128, 0, stream>>>(x, e);
  transpose_conv_kernel<<<dim3(4, 16, S1), 256, 0, stream>>>(W0, W0Th, W0Tl, 120, H, DPAD, H, 8);
  transpose_conv_kernel<<<dim3(16, 16, S1), 256, 0, stream>>>(W1, W1Th, nullptr, H, H, H, H, 0);
  transpose_conv_kernel<<<dim3(16, 16, S1), 256, 0, stream>>>(W2, W2Th, nullptr, H, H, H, H, 0);
  transpose_conv_kernel<<<dim3(16, 4, S1), 256, 0, stream>>>(Wf, WfTh, WfTl, H, OUTC, H, OUTPAD, 0);

  const size_t ldsFused = (size_t)(2 * 64 + 2 * 512) * 64 * 2;   // 147456 B
  const size_t ldsOut   = (size_t)(128 + 112 + 112) * 64 * 2;    // 45056 B

  int sb = 0;
  for (int pass = 0; pass < nPasses; ++pass) {
    const int nz = baseSz + (pass < remSz ? 1 : 0);
    const int gridFused = (BATCH / 64) * nz;   // 64*nz, %8==0
    // layer 0: e (shared) -> P2  [fused gelu+LN, W-split]
    gemm_ln_kernel<false, true><<<gridFused, 512, ldsFused, stream>>>(
        e, W0Th + (size_t)sb * H * DPAD, W0Tl + (size_t)sb * H * DPAD,
        b0 + sb * H, ln0s + sb * H, ln0b + sb * H, P2, BATCH, DPAD, 0);
    // layer 1: P2 -> P1 (residual = P2)  [fused, single-f16 W1]
    gemm_ln_kernel<true, false><<<gridFused, 512, ldsFused, stream>>>(
        P2, W1Th + (size_t)sb * H * H, nullptr,
        b1 + sb * H, ln1s + sb * H, ln1b + sb * H, P1, BATCH, H, BATCH * H);
    // layer 2: P1 -> P2 (residual = P1)  [fused, single-f16 W2]
    gemm_ln_kernel<true, false><<<gridFused, 512, ldsFused, stream>>>(
        P1, W2Th + (size_t)sb * H * H, nullptr,
        b2 + sb * H, ln2s + sb * H, ln2b + sb * H, P2, BATCH, H, BATCH * H);
    // final projection: P2 -> pbuf (f32, W-split Wf)
    gemm_out_kernel<<<dim3(BATCH / 128, 1, nz), 512, ldsOut, stream>>>(
        P2, WfTh + (size_t)sb * OUTPAD * H, WfTl + (size_t)sb * OUTPAD * H,
        bfb + sb * OUTC, pbuf + (size_t)sb * BATCH * OUTC, BATCH, H, BATCH * H);
    sb += nz;
  }

  spline_kernel<<<dim3(16, 32), 128, 0, stream>>>(x, bias0, pbuf, out0, ladb);
  lad_reduce_kernel<<<BATCH / 256, 256, 0, stream>>>(ladb, out1);
}